// Round 1
// baseline (275.664 us; speedup 1.0000x reference)
//
#include <hip/hip_runtime.h>
#include <hip/hip_bf16.h>

#define HW 4096

// ---------------- K0: transpose w2 (IC*MID, MID, 3,3) -> w2t[g][ci*9+k][co] ----------------
__global__ __launch_bounds__(256) void k0_wt(const float* __restrict__ w2, float* __restrict__ w2t) {
    int idx = blockIdx.x * 256 + threadIdx.x;      // 8 * 9216 = 73728
    if (idx >= 8 * 9216) return;
    int g = idx / 9216;
    int r = idx % 9216;
    int co = r & 31;
    int t  = r >> 5;                                // ci*9 + ky*3 + kx
    w2t[idx] = w2[(size_t)(g * 32 + co) * 288 + t];
}

// ---------------- K1: relu(x) -> 1x1 conv (16->32 per group) -> relu -> h1 ----------------
__global__ __launch_bounds__(256) void k1_conv1(const float* __restrict__ x, const float* __restrict__ w1,
                                                const float* __restrict__ b1, float* __restrict__ h1) {
    int bi = blockIdx.x;                 // ((b*8 + g)*16 + chunk)
    int chunk = bi & 15;
    int g = (bi >> 4) & 7;
    int b = bi >> 7;
    int pos = chunk * 256 + threadIdx.x;

    const float* xb = x + (size_t)(b * 128 + g * 16) * HW + pos;
    float xv[16];
#pragma unroll
    for (int i = 0; i < 16; ++i) xv[i] = fmaxf(xb[i * HW], 0.f);

    const float* wg = w1 + g * 32 * 16;  // uniform across block -> scalar loads
    const float* bg = b1 + g * 32;
    float* hb = h1 + (size_t)(b * 256 + g * 32) * HW + pos;
#pragma unroll
    for (int m = 0; m < 32; ++m) {
        float acc = bg[m];
#pragma unroll
        for (int i = 0; i < 16; ++i) acc = fmaf(xv[i], wg[m * 16 + i], acc);
        hb[m * HW] = fmaxf(acc, 0.f);
    }
}

// ---------------- K2: grouped 3x3 SAME conv (32->32 per group) + relu -> h2 ----------------
__global__ __launch_bounds__(256) void k2_conv2(const float* __restrict__ h1, const float* __restrict__ w2t,
                                                const float* __restrict__ b2, float* __restrict__ h2) {
    __shared__ float in_s[32][6][35];   // 32 ci x 6 rows x (34 cols, pad to 35)
    __shared__ float w_s[9216];         // [ci*9+k][co]

    int bi = blockIdx.x;                // b*256 + g*32 + rt*2 + ct
    int ct = bi & 1;
    int rt = (bi >> 1) & 15;
    int g  = (bi >> 5) & 7;
    int b  = bi >> 8;
    int y0 = rt * 4, x0 = ct * 32;
    int tid = threadIdx.x;

    const float* wg = w2t + g * 9216;
    for (int i = tid; i < 9216; i += 256) w_s[i] = wg[i];

    const float* hb = h1 + (size_t)(b * 256 + g * 32) * HW;
    for (int i = tid; i < 32 * 6 * 34; i += 256) {
        int c  = i % 34;
        int r  = (i / 34) % 6;
        int ci = i / 204;
        int gy = y0 + r - 1, gx = x0 + c - 1;
        float v = 0.f;
        if (gy >= 0 && gy < 64 && gx >= 0 && gx < 64) v = hb[ci * HW + gy * 64 + gx];
        in_s[ci][r][c] = v;
    }
    __syncthreads();

    int cog  = tid >> 5;          // 0..7 -> co = cog*4 + j
    int posg = tid & 31;
    int r0 = posg >> 3;           // 0..3 output row in tile
    int c0 = (posg & 7) * 4;      // output col group

    float acc[4][4];
#pragma unroll
    for (int j = 0; j < 4; ++j) {
        float bb = b2[g * 32 + cog * 4 + j];
#pragma unroll
        for (int p = 0; p < 4; ++p) acc[j][p] = bb;
    }

    for (int ci = 0; ci < 32; ++ci) {
        float iv[3][6];
#pragma unroll
        for (int ky = 0; ky < 3; ++ky)
#pragma unroll
            for (int c = 0; c < 6; ++c) iv[ky][c] = in_s[ci][r0 + ky][c0 + c];
        const float* wc = &w_s[ci * 288];
#pragma unroll
        for (int ky = 0; ky < 3; ++ky)
#pragma unroll
            for (int kx = 0; kx < 3; ++kx) {
                const float4 wv = *reinterpret_cast<const float4*>(&wc[(ky * 3 + kx) * 32 + cog * 4]);
#pragma unroll
                for (int p = 0; p < 4; ++p) {
                    float in = iv[ky][kx + p];
                    acc[0][p] = fmaf(in, wv.x, acc[0][p]);
                    acc[1][p] = fmaf(in, wv.y, acc[1][p]);
                    acc[2][p] = fmaf(in, wv.z, acc[2][p]);
                    acc[3][p] = fmaf(in, wv.w, acc[3][p]);
                }
            }
    }

    float* ob = h2 + (size_t)(b * 256 + g * 32) * HW + (y0 + r0) * 64 + (x0 + c0);
#pragma unroll
    for (int j = 0; j < 4; ++j) {
        float4 o;
        o.x = fmaxf(acc[j][0], 0.f);
        o.y = fmaxf(acc[j][1], 0.f);
        o.z = fmaxf(acc[j][2], 0.f);
        o.w = fmaxf(acc[j][3], 0.f);
        *reinterpret_cast<float4*>(&ob[(cog * 4 + j) * HW]) = o;
    }
}

// ---------------- K3: 1x1 conv3 (32->128 per group) + full dynamic routing -> s, meanAcc ----------------
__global__ __launch_bounds__(512, 2) void k3_route(const float* __restrict__ h2, const float* __restrict__ w3,
                                                   const float* __restrict__ b3, float* __restrict__ sOut,
                                                   float* __restrict__ meanAcc) {
    int b = blockIdx.x >> 6;
    int pos = ((blockIdx.x & 63) << 6) + (threadIdx.x & 63);
    int oc = __builtin_amdgcn_readfirstlane(threadIdx.x >> 6);   // wave-uniform -> scalar weight loads

    const float* hb = h2 + (size_t)b * 256 * HW + pos;

    float u[8][16];
    float scale[8];
#pragma unroll
    for (int ic = 0; ic < 8; ++ic) {
        float hv[32];
#pragma unroll
        for (int m = 0; m < 32; ++m) hv[m] = hb[(ic * 32 + m) * HW];
        const float* wt = w3 + (size_t)(ic * 128 + oc * 16) * 32;
        const float* bt = b3 + (ic * 128 + oc * 16);
        float sq = 0.f;
#pragma unroll
        for (int od = 0; od < 16; ++od) {
            float a = bt[od];
#pragma unroll
            for (int m = 0; m < 32; ++m) a = fmaf(hv[m], wt[od * 32 + m], a);
            u[ic][od] = a;
            sq = fmaf(a, a, sq);
        }
        scale[ic] = sq / ((0.5f + sq) * (sqrtf(sq + 1e-6f) + 1e-6f));
    }

    float br[8];
#pragma unroll
    for (int ic = 0; ic < 8; ++ic) br[ic] = 0.f;

#pragma unroll
    for (int it = 0; it < 2; ++it) {
        float csc[8];
#pragma unroll
        for (int ic = 0; ic < 8; ++ic) csc[ic] = scale[ic] / (1.f + __expf(-br[ic]));
        float sv[16];
        float sq = 0.f;
#pragma unroll
        for (int od = 0; od < 16; ++od) {
            float a = 0.f;
#pragma unroll
            for (int ic = 0; ic < 8; ++ic) a = fmaf(u[ic][od], csc[ic], a);
            sv[od] = a;
            sq = fmaf(a, a, sq);
        }
        float f = sq / ((0.5f + sq) * (sqrtf(sq + 1e-6f) + 1e-6f));
#pragma unroll
        for (int ic = 0; ic < 8; ++ic) {
            float d = 0.f;
#pragma unroll
            for (int od = 0; od < 16; ++od) d = fmaf(u[ic][od], sv[od], d);
            br[ic] = fmaf(scale[ic] * f, d, br[ic]);
        }
    }

    float c_[8];
#pragma unroll
    for (int ic = 0; ic < 8; ++ic) c_[ic] = 1.f / (1.f + __expf(-br[ic]));

    float* sb = sOut + (size_t)((b * 8 + oc) * 16) * HW + pos;
#pragma unroll
    for (int od = 0; od < 16; ++od) {
        float a = 0.f;
#pragma unroll
        for (int ic = 0; ic < 8; ++ic) a = fmaf(u[ic][od], c_[ic], a);
        sb[od * HW] = a;
        float r = a;
#pragma unroll
        for (int m = 1; m < 64; m <<= 1) r += __shfl_xor(r, m);
        if ((threadIdx.x & 63) == 0) atomicAdd(&meanAcc[(b * 8 + oc) * 16 + od], r);
    }
}

// ---------------- K4: avg = sum_od s*mean_hw; partial stats per (b,oc) ----------------
__global__ __launch_bounds__(256) void k4_avg(const float* __restrict__ sIn, const float* __restrict__ meanAcc,
                                              float* __restrict__ avg, float* __restrict__ stats) {
    int bi = blockIdx.x;                 // (b*8+oc)*16 + chunk
    int chunk = bi & 15;
    int bo = bi >> 4;
    int pos = chunk * 256 + threadIdx.x;

    const float* sb = sIn + (size_t)bo * 16 * HW + pos;
    const float* mh = meanAcc + bo * 16;
    float a = 0.f;
#pragma unroll
    for (int od = 0; od < 16; ++od) a = fmaf(sb[od * HW], mh[od] * (1.f / 4096.f), a);
    avg[(size_t)bo * HW + pos] = a;

    float s1 = a, s2 = a * a;
#pragma unroll
    for (int m = 1; m < 64; m <<= 1) {
        s1 += __shfl_xor(s1, m);
        s2 += __shfl_xor(s2, m);
    }
    if ((threadIdx.x & 63) == 0) {
        atomicAdd(&stats[bo * 2],     s1);
        atomicAdd(&stats[bo * 2 + 1], s2);
    }
}

// ---------------- K5: normalize, attn gate, residual ----------------
__global__ __launch_bounds__(256) void k5_out(const float* __restrict__ sIn, const float* __restrict__ x,
                                              const float* __restrict__ avg, const float* __restrict__ stats,
                                              const float* __restrict__ aw, const float* __restrict__ ab,
                                              float* __restrict__ out) {
    int bi = blockIdx.x;                 // (b*8+oc)*16 + chunk
    int chunk = bi & 15;
    int bo = bi >> 4;
    int oc = bo & 7;
    int pos = chunk * 256 + threadIdx.x;

    float sum = stats[bo * 2], sumsq = stats[bo * 2 + 1];
    float m   = sum * (1.f / 4096.f);
    float var = (sumsq - 4096.f * m * m) * (1.f / 4095.f);
    float sd  = sqrtf(fmaxf(var, 0.f)) + 1e-6f;

    float t   = (avg[(size_t)bo * HW + pos] - m) / sd * aw[oc] + ab[oc];
    float sig = 1.f / (1.f + __expf(-t));

    const float* sb = sIn + (size_t)bo * 16 * HW + pos;
    const float* xb = x   + (size_t)bo * 16 * HW + pos;   // channel oc*16+od == bo*16+od - b*... (matches: bo*16 = b*128 + oc*16)
    float* ob = out + (size_t)bo * 16 * HW + pos;
#pragma unroll
    for (int od = 0; od < 16; ++od) ob[od * HW] = fmaf(sb[od * HW], sig, xb[od * HW]);
}

extern "C" void kernel_launch(void* const* d_in, const int* in_sizes, int n_in,
                              void* d_out, int out_size, void* d_ws, size_t ws_size,
                              hipStream_t stream) {
    const float* x  = (const float*)d_in[0];
    const float* w1 = (const float*)d_in[1];
    const float* b1 = (const float*)d_in[2];
    const float* w2 = (const float*)d_in[3];
    const float* b2 = (const float*)d_in[4];
    const float* w3 = (const float*)d_in[5];
    const float* b3 = (const float*)d_in[6];
    const float* aw = (const float*)d_in[7];
    const float* ab = (const float*)d_in[8];

    float* ws      = (float*)d_ws;
    float* h1      = ws;                     // 8*256*4096  = 8388608
    float* h2      = h1 + 8388608;           // 8388608
    float* sbuf    = h2 + 8388608;           // 8*8*16*4096 = 4194304
    float* avg     = sbuf + 4194304;         // 262144
    float* meanAcc = avg + 262144;           // 1024
    float* stats   = meanAcc + 1024;         // 128
    float* w2t     = stats + 128;            // 73728

    hipMemsetAsync(meanAcc, 0, (1024 + 128) * sizeof(float), stream);
    k0_wt   <<<288, 256, 0, stream>>>(w2, w2t);
    k1_conv1<<<1024, 256, 0, stream>>>(x, w1, b1, h1);
    k2_conv2<<<2048, 256, 0, stream>>>(h1, w2t, b2, h2);
    k3_route<<<512, 512, 0, stream>>>(h2, w3, b3, sbuf, meanAcc);
    k4_avg  <<<1024, 256, 0, stream>>>(sbuf, meanAcc, avg, stats);
    k5_out  <<<1024, 256, 0, stream>>>(sbuf, x, avg, stats, aw, ab, (float*)d_out);
}

// Round 2
// 272.319 us; speedup vs baseline: 1.0123x; 1.0123x over previous
//
#include <hip/hip_runtime.h>
#include <hip/hip_bf16.h>

#define HW 4096

// ---------------- K0: transpose w2 (IC*MID, MID, 3,3) -> w2t[g][ci*9+k][co] ----------------
__global__ __launch_bounds__(256) void k0_wt(const float* __restrict__ w2, float* __restrict__ w2t) {
    int idx = blockIdx.x * 256 + threadIdx.x;      // 8 * 9216 = 73728
    if (idx >= 8 * 9216) return;
    int g = idx / 9216;
    int r = idx % 9216;
    int co = r & 31;
    int t  = r >> 5;                                // ci*9 + ky*3 + kx
    w2t[idx] = w2[(size_t)(g * 32 + co) * 288 + t];
}

// ---------------- K1: relu(x) -> 1x1 conv (16->32 per group) -> relu -> h1 ----------------
__global__ __launch_bounds__(256) void k1_conv1(const float* __restrict__ x, const float* __restrict__ w1,
                                                const float* __restrict__ b1, float* __restrict__ h1) {
    int bi = blockIdx.x;                 // ((b*8 + g)*16 + chunk)
    int chunk = bi & 15;
    int g = (bi >> 4) & 7;
    int b = bi >> 7;
    int pos = chunk * 256 + threadIdx.x;

    const float* xb = x + (size_t)(b * 128 + g * 16) * HW + pos;
    float xv[16];
#pragma unroll
    for (int i = 0; i < 16; ++i) xv[i] = fmaxf(xb[i * HW], 0.f);

    const float* wg = w1 + g * 32 * 16;  // uniform across block -> scalar loads
    const float* bg = b1 + g * 32;
    float* hb = h1 + (size_t)(b * 256 + g * 32) * HW + pos;
#pragma unroll
    for (int m = 0; m < 32; ++m) {
        float acc = bg[m];
#pragma unroll
        for (int i = 0; i < 16; ++i) acc = fmaf(xv[i], wg[m * 16 + i], acc);
        hb[m * HW] = fmaxf(acc, 0.f);
    }
}

// ---------------- K2: grouped 3x3 SAME conv (32->32 per group) + relu -> h2 ----------------
__global__ __launch_bounds__(256) void k2_conv2(const float* __restrict__ h1, const float* __restrict__ w2t,
                                                const float* __restrict__ b2, float* __restrict__ h2) {
    __shared__ float in_s[32][6][35];   // 32 ci x 6 rows x (34 cols, pad to 35)
    __shared__ float w_s[9216];         // [ci*9+k][co]

    int bi = blockIdx.x;                // b*256 + g*32 + rt*2 + ct
    int ct = bi & 1;
    int rt = (bi >> 1) & 15;
    int g  = (bi >> 5) & 7;
    int b  = bi >> 8;
    int y0 = rt * 4, x0 = ct * 32;
    int tid = threadIdx.x;

    const float* wg = w2t + g * 9216;
    for (int i = tid; i < 9216; i += 256) w_s[i] = wg[i];

    const float* hb = h1 + (size_t)(b * 256 + g * 32) * HW;
    for (int i = tid; i < 32 * 6 * 34; i += 256) {
        int c  = i % 34;
        int r  = (i / 34) % 6;
        int ci = i / 204;
        int gy = y0 + r - 1, gx = x0 + c - 1;
        float v = 0.f;
        if (gy >= 0 && gy < 64 && gx >= 0 && gx < 64) v = hb[ci * HW + gy * 64 + gx];
        in_s[ci][r][c] = v;
    }
    __syncthreads();

    int cog  = tid >> 5;          // 0..7 -> co = cog*4 + j
    int posg = tid & 31;
    int r0 = posg >> 3;           // 0..3 output row in tile
    int c0 = (posg & 7) * 4;      // output col group

    float acc[4][4];
#pragma unroll
    for (int j = 0; j < 4; ++j) {
        float bb = b2[g * 32 + cog * 4 + j];
#pragma unroll
        for (int p = 0; p < 4; ++p) acc[j][p] = bb;
    }

    for (int ci = 0; ci < 32; ++ci) {
        float iv[3][6];
#pragma unroll
        for (int ky = 0; ky < 3; ++ky)
#pragma unroll
            for (int c = 0; c < 6; ++c) iv[ky][c] = in_s[ci][r0 + ky][c0 + c];
        const float* wc = &w_s[ci * 288];
#pragma unroll
        for (int ky = 0; ky < 3; ++ky)
#pragma unroll
            for (int kx = 0; kx < 3; ++kx) {
                const float4 wv = *reinterpret_cast<const float4*>(&wc[(ky * 3 + kx) * 32 + cog * 4]);
#pragma unroll
                for (int p = 0; p < 4; ++p) {
                    float in = iv[ky][kx + p];
                    acc[0][p] = fmaf(in, wv.x, acc[0][p]);
                    acc[1][p] = fmaf(in, wv.y, acc[1][p]);
                    acc[2][p] = fmaf(in, wv.z, acc[2][p]);
                    acc[3][p] = fmaf(in, wv.w, acc[3][p]);
                }
            }
    }

    float* ob = h2 + (size_t)(b * 256 + g * 32) * HW + (y0 + r0) * 64 + (x0 + c0);
#pragma unroll
    for (int j = 0; j < 4; ++j) {
        float4 o;
        o.x = fmaxf(acc[j][0], 0.f);
        o.y = fmaxf(acc[j][1], 0.f);
        o.z = fmaxf(acc[j][2], 0.f);
        o.w = fmaxf(acc[j][3], 0.f);
        *reinterpret_cast<float4*>(&ob[(cog * 4 + j) * HW]) = o;
    }
}

// ---------------- K3: 1x1 conv3 (32->128 per group) + full dynamic routing -> s, meanAcc ----------------
// amdgpu_waves_per_eu(2,2): pin the allocator at 2 waves/EU (256 VGPR budget).
// Round-1 showed the occupancy heuristic picking 116 VGPR and spilling u[8][16].
__global__ __attribute__((amdgpu_flat_work_group_size(512, 512), amdgpu_waves_per_eu(2, 2)))
void k3_route(const float* __restrict__ h2, const float* __restrict__ w3,
              const float* __restrict__ b3, float* __restrict__ sOut,
              float* __restrict__ meanAcc) {
    int b = blockIdx.x >> 6;
    int pos = ((blockIdx.x & 63) << 6) + (threadIdx.x & 63);
    int oc = __builtin_amdgcn_readfirstlane(threadIdx.x >> 6);   // wave-uniform -> scalar weight loads

    const float* hb = h2 + (size_t)b * 256 * HW + pos;

    float u[8][16];
    float scale[8];
#pragma unroll
    for (int ic = 0; ic < 8; ++ic) {
        const float* wt = w3 + (size_t)(ic * 128 + oc * 16) * 32;
        const float* bt = b3 + (ic * 128 + oc * 16);
#pragma unroll
        for (int od = 0; od < 16; ++od) u[ic][od] = bt[od];
        // m-chunked: keep only 8 h-values live at a time (peak regs ~ 128 u + 8 hv)
#pragma unroll
        for (int mc = 0; mc < 4; ++mc) {
            float hv[8];
#pragma unroll
            for (int m = 0; m < 8; ++m) hv[m] = hb[(ic * 32 + mc * 8 + m) * HW];
#pragma unroll
            for (int od = 0; od < 16; ++od)
#pragma unroll
                for (int m = 0; m < 8; ++m)
                    u[ic][od] = fmaf(hv[m], wt[od * 32 + mc * 8 + m], u[ic][od]);
        }
        float sq = 0.f;
#pragma unroll
        for (int od = 0; od < 16; ++od) sq = fmaf(u[ic][od], u[ic][od], sq);
        scale[ic] = sq / ((0.5f + sq) * (sqrtf(sq + 1e-6f) + 1e-6f));
    }

    float br[8];
#pragma unroll
    for (int ic = 0; ic < 8; ++ic) br[ic] = 0.f;

#pragma unroll
    for (int it = 0; it < 2; ++it) {
        float csc[8];
#pragma unroll
        for (int ic = 0; ic < 8; ++ic) csc[ic] = scale[ic] / (1.f + __expf(-br[ic]));
        float sv[16];
        float sq = 0.f;
#pragma unroll
        for (int od = 0; od < 16; ++od) {
            float a = 0.f;
#pragma unroll
            for (int ic = 0; ic < 8; ++ic) a = fmaf(u[ic][od], csc[ic], a);
            sv[od] = a;
            sq = fmaf(a, a, sq);
        }
        float f = sq / ((0.5f + sq) * (sqrtf(sq + 1e-6f) + 1e-6f));
#pragma unroll
        for (int ic = 0; ic < 8; ++ic) {
            float d = 0.f;
#pragma unroll
            for (int od = 0; od < 16; ++od) d = fmaf(u[ic][od], sv[od], d);
            br[ic] = fmaf(scale[ic] * f, d, br[ic]);
        }
    }

    float c_[8];
#pragma unroll
    for (int ic = 0; ic < 8; ++ic) c_[ic] = 1.f / (1.f + __expf(-br[ic]));

    float* sb = sOut + (size_t)((b * 8 + oc) * 16) * HW + pos;
#pragma unroll
    for (int od = 0; od < 16; ++od) {
        float a = 0.f;
#pragma unroll
        for (int ic = 0; ic < 8; ++ic) a = fmaf(u[ic][od], c_[ic], a);
        sb[od * HW] = a;
        float r = a;
#pragma unroll
        for (int m = 1; m < 64; m <<= 1) r += __shfl_xor(r, m);
        if ((threadIdx.x & 63) == 0) atomicAdd(&meanAcc[(b * 8 + oc) * 16 + od], r);
    }
}

// ---------------- K4: avg = sum_od s*mean_hw; partial stats per (b,oc) ----------------
__global__ __launch_bounds__(256) void k4_avg(const float* __restrict__ sIn, const float* __restrict__ meanAcc,
                                              float* __restrict__ avg, float* __restrict__ stats) {
    int bi = blockIdx.x;                 // (b*8+oc)*16 + chunk
    int chunk = bi & 15;
    int bo = bi >> 4;
    int pos = chunk * 256 + threadIdx.x;

    const float* sb = sIn + (size_t)bo * 16 * HW + pos;
    const float* mh = meanAcc + bo * 16;
    float a = 0.f;
#pragma unroll
    for (int od = 0; od < 16; ++od) a = fmaf(sb[od * HW], mh[od] * (1.f / 4096.f), a);
    avg[(size_t)bo * HW + pos] = a;

    float s1 = a, s2 = a * a;
#pragma unroll
    for (int m = 1; m < 64; m <<= 1) {
        s1 += __shfl_xor(s1, m);
        s2 += __shfl_xor(s2, m);
    }
    if ((threadIdx.x & 63) == 0) {
        atomicAdd(&stats[bo * 2],     s1);
        atomicAdd(&stats[bo * 2 + 1], s2);
    }
}

// ---------------- K5: normalize, attn gate, residual ----------------
__global__ __launch_bounds__(256) void k5_out(const float* __restrict__ sIn, const float* __restrict__ x,
                                              const float* __restrict__ avg, const float* __restrict__ stats,
                                              const float* __restrict__ aw, const float* __restrict__ ab,
                                              float* __restrict__ out) {
    int bi = blockIdx.x;                 // (b*8+oc)*16 + chunk
    int chunk = bi & 15;
    int bo = bi >> 4;
    int oc = bo & 7;
    int pos = chunk * 256 + threadIdx.x;

    float sum = stats[bo * 2], sumsq = stats[bo * 2 + 1];
    float m   = sum * (1.f / 4096.f);
    float var = (sumsq - 4096.f * m * m) * (1.f / 4095.f);
    float sd  = sqrtf(fmaxf(var, 0.f)) + 1e-6f;

    float t   = (avg[(size_t)bo * HW + pos] - m) / sd * aw[oc] + ab[oc];
    float sig = 1.f / (1.f + __expf(-t));

    const float* sb = sIn + (size_t)bo * 16 * HW + pos;
    const float* xb = x   + (size_t)bo * 16 * HW + pos;   // bo*16 = b*128 + oc*16: matches x channel layout
    float* ob = out + (size_t)bo * 16 * HW + pos;
#pragma unroll
    for (int od = 0; od < 16; ++od) ob[od * HW] = fmaf(sb[od * HW], sig, xb[od * HW]);
}

extern "C" void kernel_launch(void* const* d_in, const int* in_sizes, int n_in,
                              void* d_out, int out_size, void* d_ws, size_t ws_size,
                              hipStream_t stream) {
    const float* x  = (const float*)d_in[0];
    const float* w1 = (const float*)d_in[1];
    const float* b1 = (const float*)d_in[2];
    const float* w2 = (const float*)d_in[3];
    const float* b2 = (const float*)d_in[4];
    const float* w3 = (const float*)d_in[5];
    const float* b3 = (const float*)d_in[6];
    const float* aw = (const float*)d_in[7];
    const float* ab = (const float*)d_in[8];

    float* ws      = (float*)d_ws;
    float* h1      = ws;                     // 8*256*4096  = 8388608
    float* h2      = h1 + 8388608;           // 8388608
    float* sbuf    = h2 + 8388608;           // 8*8*16*4096 = 4194304
    float* avg     = sbuf + 4194304;         // 262144
    float* meanAcc = avg + 262144;           // 1024
    float* stats   = meanAcc + 1024;         // 128
    float* w2t     = stats + 128;            // 73728

    hipMemsetAsync(meanAcc, 0, (1024 + 128) * sizeof(float), stream);
    k0_wt   <<<288, 256, 0, stream>>>(w2, w2t);
    k1_conv1<<<1024, 256, 0, stream>>>(x, w1, b1, h1);
    k2_conv2<<<2048, 256, 0, stream>>>(h1, w2t, b2, h2);
    k3_route<<<512, 512, 0, stream>>>(h2, w3, b3, sbuf, meanAcc);
    k4_avg  <<<1024, 256, 0, stream>>>(sbuf, meanAcc, avg, stats);
    k5_out  <<<1024, 256, 0, stream>>>(sbuf, x, avg, stats, aw, ab, (float*)d_out);
}

// Round 3
// 271.901 us; speedup vs baseline: 1.0138x; 1.0015x over previous
//
#include <hip/hip_runtime.h>
#include <hip/hip_bf16.h>
#include <hip/hip_fp16.h>

#define HW 4096

// ---------------- K0: transpose w2 (IC*MID, MID, 3,3) -> w2t[g][ci*9+k][co] ----------------
__global__ __launch_bounds__(256) void k0_wt(const float* __restrict__ w2, float* __restrict__ w2t) {
    int idx = blockIdx.x * 256 + threadIdx.x;      // 8 * 9216 = 73728
    if (idx >= 8 * 9216) return;
    int g = idx / 9216;
    int r = idx % 9216;
    int co = r & 31;
    int t  = r >> 5;                                // ci*9 + ky*3 + kx
    w2t[idx] = w2[(size_t)(g * 32 + co) * 288 + t];
}

// ---------------- K1: relu(x) -> 1x1 conv (16->32 per group) -> relu -> h1 ----------------
__global__ __launch_bounds__(256) void k1_conv1(const float* __restrict__ x, const float* __restrict__ w1,
                                                const float* __restrict__ b1, float* __restrict__ h1) {
    int bi = blockIdx.x;                 // ((b*8 + g)*16 + chunk)
    int chunk = bi & 15;
    int g = (bi >> 4) & 7;
    int b = bi >> 7;
    int pos = chunk * 256 + threadIdx.x;

    const float* xb = x + (size_t)(b * 128 + g * 16) * HW + pos;
    float xv[16];
#pragma unroll
    for (int i = 0; i < 16; ++i) xv[i] = fmaxf(xb[i * HW], 0.f);

    const float* wg = w1 + g * 32 * 16;  // uniform across block -> scalar loads
    const float* bg = b1 + g * 32;
    float* hb = h1 + (size_t)(b * 256 + g * 32) * HW + pos;
#pragma unroll
    for (int m = 0; m < 32; ++m) {
        float acc = bg[m];
#pragma unroll
        for (int i = 0; i < 16; ++i) acc = fmaf(xv[i], wg[m * 16 + i], acc);
        hb[m * HW] = fmaxf(acc, 0.f);
    }
}

// ---------------- K2: grouped 3x3 SAME conv (32->32 per group) + relu -> h2 ----------------
__global__ __launch_bounds__(256) void k2_conv2(const float* __restrict__ h1, const float* __restrict__ w2t,
                                                const float* __restrict__ b2, float* __restrict__ h2) {
    __shared__ float in_s[32][6][35];   // 32 ci x 6 rows x (34 cols, pad to 35)
    __shared__ float w_s[9216];         // [ci*9+k][co]

    int bi = blockIdx.x;                // b*256 + g*32 + rt*2 + ct
    int ct = bi & 1;
    int rt = (bi >> 1) & 15;
    int g  = (bi >> 5) & 7;
    int b  = bi >> 8;
    int y0 = rt * 4, x0 = ct * 32;
    int tid = threadIdx.x;

    const float* wg = w2t + g * 9216;
    for (int i = tid; i < 9216; i += 256) w_s[i] = wg[i];

    const float* hb = h1 + (size_t)(b * 256 + g * 32) * HW;
    for (int i = tid; i < 32 * 6 * 34; i += 256) {
        int c  = i % 34;
        int r  = (i / 34) % 6;
        int ci = i / 204;
        int gy = y0 + r - 1, gx = x0 + c - 1;
        float v = 0.f;
        if (gy >= 0 && gy < 64 && gx >= 0 && gx < 64) v = hb[ci * HW + gy * 64 + gx];
        in_s[ci][r][c] = v;
    }
    __syncthreads();

    int cog  = tid >> 5;          // 0..7 -> co = cog*4 + j
    int posg = tid & 31;
    int r0 = posg >> 3;           // 0..3 output row in tile
    int c0 = (posg & 7) * 4;      // output col group

    float acc[4][4];
#pragma unroll
    for (int j = 0; j < 4; ++j) {
        float bb = b2[g * 32 + cog * 4 + j];
#pragma unroll
        for (int p = 0; p < 4; ++p) acc[j][p] = bb;
    }

    for (int ci = 0; ci < 32; ++ci) {
        float iv[3][6];
#pragma unroll
        for (int ky = 0; ky < 3; ++ky)
#pragma unroll
            for (int c = 0; c < 6; ++c) iv[ky][c] = in_s[ci][r0 + ky][c0 + c];
        const float* wc = &w_s[ci * 288];
#pragma unroll
        for (int ky = 0; ky < 3; ++ky)
#pragma unroll
            for (int kx = 0; kx < 3; ++kx) {
                const float4 wv = *reinterpret_cast<const float4*>(&wc[(ky * 3 + kx) * 32 + cog * 4]);
#pragma unroll
                for (int p = 0; p < 4; ++p) {
                    float in = iv[ky][kx + p];
                    acc[0][p] = fmaf(in, wv.x, acc[0][p]);
                    acc[1][p] = fmaf(in, wv.y, acc[1][p]);
                    acc[2][p] = fmaf(in, wv.z, acc[2][p]);
                    acc[3][p] = fmaf(in, wv.w, acc[3][p]);
                }
            }
    }

    float* ob = h2 + (size_t)(b * 256 + g * 32) * HW + (y0 + r0) * 64 + (x0 + c0);
#pragma unroll
    for (int j = 0; j < 4; ++j) {
        float4 o;
        o.x = fmaxf(acc[j][0], 0.f);
        o.y = fmaxf(acc[j][1], 0.f);
        o.z = fmaxf(acc[j][2], 0.f);
        o.w = fmaxf(acc[j][3], 0.f);
        *reinterpret_cast<float4*>(&ob[(cog * 4 + j) * HW]) = o;
    }
}

// ---------------- K3: 1x1 conv3 (32->128 per group) + full dynamic routing -> s, meanAcc ----------------
// u stored as packed fp16 half2 (64 VGPRs instead of 128 f32) so the kernel
// fits the allocator's ~96-128 VGPR budget with NO scratch spill. All
// accumulation stays f32; only storage of u is fp16 (rel err ~5e-4, well
// under the 0.1 output threshold).
__global__ __launch_bounds__(512) void k3_route(const float* __restrict__ h2, const float* __restrict__ w3,
                                                const float* __restrict__ b3, float* __restrict__ sOut,
                                                float* __restrict__ meanAcc) {
    int b = blockIdx.x >> 6;
    int pos = ((blockIdx.x & 63) << 6) + (threadIdx.x & 63);
    int oc = __builtin_amdgcn_readfirstlane(threadIdx.x >> 6);   // wave-uniform -> scalar weight loads

    const float* hb = h2 + (size_t)b * 256 * HW + pos;

    __half2 uh[8][8];
    float scale[8];
#pragma unroll
    for (int ic = 0; ic < 8; ++ic) {
        const float* wt = w3 + (size_t)(ic * 128 + oc * 16) * 32;
        const float* bt = b3 + (ic * 128 + oc * 16);
        float ut[16];
#pragma unroll
        for (int od = 0; od < 16; ++od) ut[od] = bt[od];
#pragma unroll
        for (int mc = 0; mc < 2; ++mc) {
            float hv[16];
#pragma unroll
            for (int m = 0; m < 16; ++m) hv[m] = hb[(ic * 32 + mc * 16 + m) * HW];
#pragma unroll
            for (int od = 0; od < 16; ++od)
#pragma unroll
                for (int m = 0; m < 16; ++m)
                    ut[od] = fmaf(hv[m], wt[od * 32 + mc * 16 + m], ut[od]);
        }
        float sq = 0.f;
#pragma unroll
        for (int od = 0; od < 16; ++od) sq = fmaf(ut[od], ut[od], sq);
        scale[ic] = sq / ((0.5f + sq) * (sqrtf(sq + 1e-6f) + 1e-6f));
#pragma unroll
        for (int j = 0; j < 8; ++j) uh[ic][j] = __floats2half2_rn(ut[2 * j], ut[2 * j + 1]);
    }

    float br[8];
#pragma unroll
    for (int ic = 0; ic < 8; ++ic) br[ic] = 0.f;

#pragma unroll
    for (int it = 0; it < 2; ++it) {
        float csc[8];
#pragma unroll
        for (int ic = 0; ic < 8; ++ic) csc[ic] = scale[ic] / (1.f + __expf(-br[ic]));
        float sv[16];
        float sq = 0.f;
#pragma unroll
        for (int j = 0; j < 8; ++j) {
            float a0 = 0.f, a1 = 0.f;
#pragma unroll
            for (int ic = 0; ic < 8; ++ic) {
                float2 f = __half22float2(uh[ic][j]);
                a0 = fmaf(f.x, csc[ic], a0);
                a1 = fmaf(f.y, csc[ic], a1);
            }
            sv[2 * j] = a0;
            sv[2 * j + 1] = a1;
            sq = fmaf(a0, a0, fmaf(a1, a1, sq));
        }
        float f = sq / ((0.5f + sq) * (sqrtf(sq + 1e-6f) + 1e-6f));
#pragma unroll
        for (int ic = 0; ic < 8; ++ic) {
            float d = 0.f;
#pragma unroll
            for (int j = 0; j < 8; ++j) {
                float2 uf = __half22float2(uh[ic][j]);
                d = fmaf(uf.x, sv[2 * j], fmaf(uf.y, sv[2 * j + 1], d));
            }
            br[ic] = fmaf(scale[ic] * f, d, br[ic]);
        }
    }

    float c_[8];
#pragma unroll
    for (int ic = 0; ic < 8; ++ic) c_[ic] = 1.f / (1.f + __expf(-br[ic]));

    float* sb = sOut + (size_t)((b * 8 + oc) * 16) * HW + pos;
#pragma unroll
    for (int j = 0; j < 8; ++j) {
        float a0 = 0.f, a1 = 0.f;
#pragma unroll
        for (int ic = 0; ic < 8; ++ic) {
            float2 uf = __half22float2(uh[ic][j]);
            a0 = fmaf(uf.x, c_[ic], a0);
            a1 = fmaf(uf.y, c_[ic], a1);
        }
        sb[(2 * j) * HW] = a0;
        sb[(2 * j + 1) * HW] = a1;
        float r0 = a0, r1 = a1;
#pragma unroll
        for (int m = 1; m < 64; m <<= 1) {
            r0 += __shfl_xor(r0, m);
            r1 += __shfl_xor(r1, m);
        }
        if ((threadIdx.x & 63) == 0) {
            atomicAdd(&meanAcc[(b * 8 + oc) * 16 + 2 * j], r0);
            atomicAdd(&meanAcc[(b * 8 + oc) * 16 + 2 * j + 1], r1);
        }
    }
}

// ---------------- K4: avg = sum_od s*mean_hw; partial stats per (b,oc) ----------------
__global__ __launch_bounds__(256) void k4_avg(const float* __restrict__ sIn, const float* __restrict__ meanAcc,
                                              float* __restrict__ avg, float* __restrict__ stats) {
    int bi = blockIdx.x;                 // (b*8+oc)*16 + chunk
    int chunk = bi & 15;
    int bo = bi >> 4;
    int pos = chunk * 256 + threadIdx.x;

    const float* sb = sIn + (size_t)bo * 16 * HW + pos;
    const float* mh = meanAcc + bo * 16;
    float a = 0.f;
#pragma unroll
    for (int od = 0; od < 16; ++od) a = fmaf(sb[od * HW], mh[od] * (1.f / 4096.f), a);
    avg[(size_t)bo * HW + pos] = a;

    float s1 = a, s2 = a * a;
#pragma unroll
    for (int m = 1; m < 64; m <<= 1) {
        s1 += __shfl_xor(s1, m);
        s2 += __shfl_xor(s2, m);
    }
    if ((threadIdx.x & 63) == 0) {
        atomicAdd(&stats[bo * 2],     s1);
        atomicAdd(&stats[bo * 2 + 1], s2);
    }
}

// ---------------- K5: normalize, attn gate, residual ----------------
__global__ __launch_bounds__(256) void k5_out(const float* __restrict__ sIn, const float* __restrict__ x,
                                              const float* __restrict__ avg, const float* __restrict__ stats,
                                              const float* __restrict__ aw, const float* __restrict__ ab,
                                              float* __restrict__ out) {
    int bi = blockIdx.x;                 // (b*8+oc)*16 + chunk
    int chunk = bi & 15;
    int bo = bi >> 4;
    int oc = bo & 7;
    int pos = chunk * 256 + threadIdx.x;

    float sum = stats[bo * 2], sumsq = stats[bo * 2 + 1];
    float m   = sum * (1.f / 4096.f);
    float var = (sumsq - 4096.f * m * m) * (1.f / 4095.f);
    float sd  = sqrtf(fmaxf(var, 0.f)) + 1e-6f;

    float t   = (avg[(size_t)bo * HW + pos] - m) / sd * aw[oc] + ab[oc];
    float sig = 1.f / (1.f + __expf(-t));

    const float* sb = sIn + (size_t)bo * 16 * HW + pos;
    const float* xb = x   + (size_t)bo * 16 * HW + pos;   // bo*16 = b*128 + oc*16: matches x channel layout
    float* ob = out + (size_t)bo * 16 * HW + pos;
#pragma unroll
    for (int od = 0; od < 16; ++od) ob[od * HW] = fmaf(sb[od * HW], sig, xb[od * HW]);
}

extern "C" void kernel_launch(void* const* d_in, const int* in_sizes, int n_in,
                              void* d_out, int out_size, void* d_ws, size_t ws_size,
                              hipStream_t stream) {
    const float* x  = (const float*)d_in[0];
    const float* w1 = (const float*)d_in[1];
    const float* b1 = (const float*)d_in[2];
    const float* w2 = (const float*)d_in[3];
    const float* b2 = (const float*)d_in[4];
    const float* w3 = (const float*)d_in[5];
    const float* b3 = (const float*)d_in[6];
    const float* aw = (const float*)d_in[7];
    const float* ab = (const float*)d_in[8];

    float* ws      = (float*)d_ws;
    float* h1      = ws;                     // 8*256*4096  = 8388608
    float* h2      = h1 + 8388608;           // 8388608
    float* sbuf    = h2 + 8388608;           // 8*8*16*4096 = 4194304
    float* avg     = sbuf + 4194304;         // 262144
    float* meanAcc = avg + 262144;           // 1024
    float* stats   = meanAcc + 1024;         // 128
    float* w2t     = stats + 128;            // 73728

    hipMemsetAsync(meanAcc, 0, (1024 + 128) * sizeof(float), stream);
    k0_wt   <<<288, 256, 0, stream>>>(w2, w2t);
    k1_conv1<<<1024, 256, 0, stream>>>(x, w1, b1, h1);
    k2_conv2<<<2048, 256, 0, stream>>>(h1, w2t, b2, h2);
    k3_route<<<512, 512, 0, stream>>>(h2, w3, b3, sbuf, meanAcc);
    k4_avg  <<<1024, 256, 0, stream>>>(sbuf, meanAcc, avg, stats);
    k5_out  <<<1024, 256, 0, stream>>>(sbuf, x, avg, stats, aw, ab, (float*)d_out);
}

// Round 4
// 270.416 us; speedup vs baseline: 1.0194x; 1.0055x over previous
//
#include <hip/hip_runtime.h>
#include <hip/hip_bf16.h>
#include <hip/hip_fp16.h>

#define HW 4096

typedef _Float16 f16x8 __attribute__((ext_vector_type(8)));
typedef float f32x4 __attribute__((ext_vector_type(4)));

static __device__ __forceinline__ __half2 u2h(unsigned int u) {
    union { unsigned int u; __half2 h; } c; c.u = u; return c.h;
}
static __device__ __forceinline__ unsigned int h2u(__half2 h) {
    union { unsigned int u; __half2 h; } c; c.h = h; return c.u;
}

// ---------------- K0: transpose w2 (IC*MID, MID, 3,3) -> w2t[g][ci*9+k][co] ----------------
__global__ __launch_bounds__(256) void k0_wt(const float* __restrict__ w2, float* __restrict__ w2t) {
    int idx = blockIdx.x * 256 + threadIdx.x;      // 8 * 9216 = 73728
    if (idx >= 8 * 9216) return;
    int g = idx / 9216;
    int r = idx % 9216;
    int co = r & 31;
    int t  = r >> 5;                                // ci*9 + ky*3 + kx
    w2t[idx] = w2[(size_t)(g * 32 + co) * 288 + t];
}

// ---------------- K0b: w3 -> fp16 MFMA A-fragment order ----------------
// w3h[p=(ic*8+oc)][lane][j] = fp16( w3[(ic*128+oc*16+od)*32 + m] ),
// od = lane&15, m = (lane>>4)*8 + j   (A-frag layout for mfma 16x16x32)
__global__ __launch_bounds__(256) void k0b_w3h(const float* __restrict__ w3, ushort* __restrict__ w3h) {
    int gi = blockIdx.x * 256 + threadIdx.x;       // 64*64*8 = 32768
    if (gi >= 32768) return;
    int j = gi & 7;
    int l = (gi >> 3) & 63;
    int p = gi >> 9;                                // ic*8+oc
    int ic = p >> 3, oc = p & 7;
    int od = l & 15;
    int m  = ((l >> 4) << 3) + j;
    __half h = __float2half(w3[(size_t)((ic * 128 + oc * 16 + od) * 32 + m)]);
    w3h[gi] = __half_as_ushort(h);
}

// ---------------- K1: relu(x) -> 1x1 conv (16->32 per group) -> relu -> h1 ----------------
__global__ __launch_bounds__(256) void k1_conv1(const float* __restrict__ x, const float* __restrict__ w1,
                                                const float* __restrict__ b1, float* __restrict__ h1) {
    int bi = blockIdx.x;                 // ((b*8 + g)*16 + chunk)
    int chunk = bi & 15;
    int g = (bi >> 4) & 7;
    int b = bi >> 7;
    int pos = chunk * 256 + threadIdx.x;

    const float* xb = x + (size_t)(b * 128 + g * 16) * HW + pos;
    float xv[16];
#pragma unroll
    for (int i = 0; i < 16; ++i) xv[i] = fmaxf(xb[i * HW], 0.f);

    const float* wg = w1 + g * 32 * 16;  // uniform across block -> scalar loads
    const float* bg = b1 + g * 32;
    float* hb = h1 + (size_t)(b * 256 + g * 32) * HW + pos;
#pragma unroll
    for (int m = 0; m < 32; ++m) {
        float acc = bg[m];
#pragma unroll
        for (int i = 0; i < 16; ++i) acc = fmaf(xv[i], wg[m * 16 + i], acc);
        hb[m * HW] = fmaxf(acc, 0.f);
    }
}

// ---------------- K2: grouped 3x3 SAME conv (32->32 per group) + relu -> h2 ----------------
__global__ __launch_bounds__(256) void k2_conv2(const float* __restrict__ h1, const float* __restrict__ w2t,
                                                const float* __restrict__ b2, float* __restrict__ h2) {
    __shared__ float in_s[32][6][35];   // 32 ci x 6 rows x (34 cols, pad to 35)
    __shared__ float w_s[9216];         // [ci*9+k][co]

    int bi = blockIdx.x;                // b*256 + g*32 + rt*2 + ct
    int ct = bi & 1;
    int rt = (bi >> 1) & 15;
    int g  = (bi >> 5) & 7;
    int b  = bi >> 8;
    int y0 = rt * 4, x0 = ct * 32;
    int tid = threadIdx.x;

    const float* wg = w2t + g * 9216;
    for (int i = tid; i < 9216; i += 256) w_s[i] = wg[i];

    const float* hb = h1 + (size_t)(b * 256 + g * 32) * HW;
    for (int i = tid; i < 32 * 6 * 34; i += 256) {
        int c  = i % 34;
        int r  = (i / 34) % 6;
        int ci = i / 204;
        int gy = y0 + r - 1, gx = x0 + c - 1;
        float v = 0.f;
        if (gy >= 0 && gy < 64 && gx >= 0 && gx < 64) v = hb[ci * HW + gy * 64 + gx];
        in_s[ci][r][c] = v;
    }
    __syncthreads();

    int cog  = tid >> 5;          // 0..7 -> co = cog*4 + j
    int posg = tid & 31;
    int r0 = posg >> 3;           // 0..3 output row in tile
    int c0 = (posg & 7) * 4;      // output col group

    float acc[4][4];
#pragma unroll
    for (int j = 0; j < 4; ++j) {
        float bb = b2[g * 32 + cog * 4 + j];
#pragma unroll
        for (int p = 0; p < 4; ++p) acc[j][p] = bb;
    }

    for (int ci = 0; ci < 32; ++ci) {
        float iv[3][6];
#pragma unroll
        for (int ky = 0; ky < 3; ++ky)
#pragma unroll
            for (int c = 0; c < 6; ++c) iv[ky][c] = in_s[ci][r0 + ky][c0 + c];
        const float* wc = &w_s[ci * 288];
#pragma unroll
        for (int ky = 0; ky < 3; ++ky)
#pragma unroll
            for (int kx = 0; kx < 3; ++kx) {
                const float4 wv = *reinterpret_cast<const float4*>(&wc[(ky * 3 + kx) * 32 + cog * 4]);
#pragma unroll
                for (int p = 0; p < 4; ++p) {
                    float in = iv[ky][kx + p];
                    acc[0][p] = fmaf(in, wv.x, acc[0][p]);
                    acc[1][p] = fmaf(in, wv.y, acc[1][p]);
                    acc[2][p] = fmaf(in, wv.z, acc[2][p]);
                    acc[3][p] = fmaf(in, wv.w, acc[3][p]);
                }
            }
    }

    float* ob = h2 + (size_t)(b * 256 + g * 32) * HW + (y0 + r0) * 64 + (x0 + c0);
#pragma unroll
    for (int j = 0; j < 4; ++j) {
        float4 o;
        o.x = fmaxf(acc[j][0], 0.f);
        o.y = fmaxf(acc[j][1], 0.f);
        o.z = fmaxf(acc[j][2], 0.f);
        o.w = fmaxf(acc[j][3], 0.f);
        *reinterpret_cast<float4*>(&ob[(cog * 4 + j) * HW]) = o;
    }
}

// ---------------- K3: conv3 via MFMA (fp16) + routing, u staged in LDS ----------------
// Block: 256 thr (4 waves), 32 pixels of one b. LDS: h2 tile [px][256ch] fp16 (16KB,
// XOR-swizzled) + u [px][1024ch] fp16 (64KB, XOR-swizzled) = 80KB -> 2 blocks/CU.
// Phase A: each wave computes 16 (ic,oc) pairs x 2 px-tiles with mfma_f32_16x16x32_f16.
// No scalar weight streams (A-frags pre-swizzled by k0b, one 16B vector load each).
// Phase B: routing per thread (px,oc), u loaded via ds_read_b128.
__global__ __launch_bounds__(256) void k3_route(const float* __restrict__ h2, const ushort* __restrict__ w3h,
                                                const float* __restrict__ b3, float* __restrict__ sOut,
                                                float* __restrict__ meanAcc) {
    __shared__ ushort h2s[32 * 256];    // [px][ch], idx = px*256 + (ch ^ ((px&7)<<3))
    __shared__ ushort u_lds[32 * 1024]; // [px][ic*128+oc*16+od], same swizzle

    int bid = blockIdx.x;
    int b   = bid >> 7;
    int px0 = (bid & 127) * 32;
    int t   = threadIdx.x;

    // ---- stage h2 tile -> fp16, transposed to [px][ch] ----
    {
        int px = t & 31, cslot = t >> 5;
        int s = (px & 7) << 3;
        const float* hb = h2 + (size_t)b * 256 * HW + px0 + px;
#pragma unroll
        for (int i = 0; i < 16; ++i) {
            int ch = i * 16 + cslot * 2;
            float v0 = hb[(size_t)ch * HW];
            float v1 = hb[(size_t)(ch + 1) * HW];
            __half2 hh = __floats2half2_rn(v0, v1);
            *(unsigned int*)&h2s[(px << 8) + (ch ^ s)] = h2u(hh);
        }
    }
    __syncthreads();

    // ---- phase A: conv3 MFMA ----
    {
        int w = t >> 6, l = t & 63;
        int lrow = l & 15, lk = l >> 4;
#pragma unroll
        for (int i = 0; i < 16; ++i) {
            int p = w * 16 + i;          // (ic*8 + oc)
            int ic = p >> 3, oc = p & 7;
            f16x8 af = *(const f16x8*)&w3h[(p * 64 + l) * 8];
            float4 bias = *(const float4*)(b3 + ic * 128 + oc * 16 + lk * 4);
#pragma unroll
            for (int pxt = 0; pxt < 2; ++pxt) {
                int px = lrow + pxt * 16;
                int s = (px & 7) << 3;
                f16x8 bf = *(const f16x8*)&h2s[(px << 8) + ((ic * 32 + lk * 8) ^ s)];
                f32x4 d = {0.f, 0.f, 0.f, 0.f};
                d = __builtin_amdgcn_mfma_f32_16x16x32_f16(af, bf, d, 0, 0, 0);
                __half2 lo = __floats2half2_rn(d[0] + bias.x, d[1] + bias.y);
                __half2 hi = __floats2half2_rn(d[2] + bias.z, d[3] + bias.w);
                uint2 wv; wv.x = h2u(lo); wv.y = h2u(hi);
                int ch = ic * 128 + oc * 16 + lk * 4;
                *(uint2*)&u_lds[(px << 10) + (ch ^ s)] = wv;
            }
        }
    }
    __syncthreads();

    // ---- phase B: routing, thread = (oc = t>>5, px = t&31) ----
    int oc = t >> 5, px = t & 31;
    int s = (px & 7) << 3;
    const ushort* ur = &u_lds[px << 10];

    __half2 uh[8][8];
    float scale[8];
#pragma unroll
    for (int ic = 0; ic < 8; ++ic) {
        uint4 ra = *(const uint4*)&ur[(ic * 128 + oc * 16 + 0) ^ s];
        uint4 rb = *(const uint4*)&ur[(ic * 128 + oc * 16 + 8) ^ s];
        uh[ic][0] = u2h(ra.x); uh[ic][1] = u2h(ra.y); uh[ic][2] = u2h(ra.z); uh[ic][3] = u2h(ra.w);
        uh[ic][4] = u2h(rb.x); uh[ic][5] = u2h(rb.y); uh[ic][6] = u2h(rb.z); uh[ic][7] = u2h(rb.w);
        float sq = 0.f;
#pragma unroll
        for (int j = 0; j < 8; ++j) {
            float2 f = __half22float2(uh[ic][j]);
            sq = fmaf(f.x, f.x, fmaf(f.y, f.y, sq));
        }
        scale[ic] = sq / ((0.5f + sq) * (sqrtf(sq + 1e-6f) + 1e-6f));
    }

    float br[8];
#pragma unroll
    for (int ic = 0; ic < 8; ++ic) br[ic] = 0.f;

#pragma unroll
    for (int it = 0; it < 2; ++it) {
        float csc[8];
#pragma unroll
        for (int ic = 0; ic < 8; ++ic) csc[ic] = scale[ic] / (1.f + __expf(-br[ic]));
        float sv[16];
        float sq = 0.f;
#pragma unroll
        for (int j = 0; j < 8; ++j) {
            float a0 = 0.f, a1 = 0.f;
#pragma unroll
            for (int ic = 0; ic < 8; ++ic) {
                float2 f = __half22float2(uh[ic][j]);
                a0 = fmaf(f.x, csc[ic], a0);
                a1 = fmaf(f.y, csc[ic], a1);
            }
            sv[2 * j] = a0;
            sv[2 * j + 1] = a1;
            sq = fmaf(a0, a0, fmaf(a1, a1, sq));
        }
        float f = sq / ((0.5f + sq) * (sqrtf(sq + 1e-6f) + 1e-6f));
#pragma unroll
        for (int ic = 0; ic < 8; ++ic) {
            float d = 0.f;
#pragma unroll
            for (int j = 0; j < 8; ++j) {
                float2 uf = __half22float2(uh[ic][j]);
                d = fmaf(uf.x, sv[2 * j], fmaf(uf.y, sv[2 * j + 1], d));
            }
            br[ic] = fmaf(scale[ic] * f, d, br[ic]);
        }
    }

    float c_[8];
#pragma unroll
    for (int ic = 0; ic < 8; ++ic) c_[ic] = 1.f / (1.f + __expf(-br[ic]));

    float* sb = sOut + (size_t)((b * 8 + oc) * 16) * HW + px0 + px;
#pragma unroll
    for (int j = 0; j < 8; ++j) {
        float a0 = 0.f, a1 = 0.f;
#pragma unroll
        for (int ic = 0; ic < 8; ++ic) {
            float2 uf = __half22float2(uh[ic][j]);
            a0 = fmaf(uf.x, c_[ic], a0);
            a1 = fmaf(uf.y, c_[ic], a1);
        }
        sb[(2 * j) * HW] = a0;
        sb[(2 * j + 1) * HW] = a1;
        float r0 = a0, r1 = a1;
#pragma unroll
        for (int m = 1; m < 32; m <<= 1) {     // reduce over px (32 lanes per oc-half)
            r0 += __shfl_xor(r0, m);
            r1 += __shfl_xor(r1, m);
        }
        if ((t & 31) == 0) {
            atomicAdd(&meanAcc[(b * 8 + oc) * 16 + 2 * j], r0);
            atomicAdd(&meanAcc[(b * 8 + oc) * 16 + 2 * j + 1], r1);
        }
    }
}

// ---------------- K4: avg = sum_od s*mean_hw; partial stats per (b,oc) ----------------
__global__ __launch_bounds__(256) void k4_avg(const float* __restrict__ sIn, const float* __restrict__ meanAcc,
                                              float* __restrict__ avg, float* __restrict__ stats) {
    int bi = blockIdx.x;                 // (b*8+oc)*16 + chunk
    int chunk = bi & 15;
    int bo = bi >> 4;
    int pos = chunk * 256 + threadIdx.x;

    const float* sb = sIn + (size_t)bo * 16 * HW + pos;
    const float* mh = meanAcc + bo * 16;
    float a = 0.f;
#pragma unroll
    for (int od = 0; od < 16; ++od) a = fmaf(sb[od * HW], mh[od] * (1.f / 4096.f), a);
    avg[(size_t)bo * HW + pos] = a;

    float s1 = a, s2 = a * a;
#pragma unroll
    for (int m = 1; m < 64; m <<= 1) {
        s1 += __shfl_xor(s1, m);
        s2 += __shfl_xor(s2, m);
    }
    if ((threadIdx.x & 63) == 0) {
        atomicAdd(&stats[bo * 2],     s1);
        atomicAdd(&stats[bo * 2 + 1], s2);
    }
}

// ---------------- K5: normalize, attn gate, residual ----------------
__global__ __launch_bounds__(256) void k5_out(const float* __restrict__ sIn, const float* __restrict__ x,
                                              const float* __restrict__ avg, const float* __restrict__ stats,
                                              const float* __restrict__ aw, const float* __restrict__ ab,
                                              float* __restrict__ out) {
    int bi = blockIdx.x;                 // (b*8+oc)*16 + chunk
    int chunk = bi & 15;
    int bo = bi >> 4;
    int oc = bo & 7;
    int pos = chunk * 256 + threadIdx.x;

    float sum = stats[bo * 2], sumsq = stats[bo * 2 + 1];
    float m   = sum * (1.f / 4096.f);
    float var = (sumsq - 4096.f * m * m) * (1.f / 4095.f);
    float sd  = sqrtf(fmaxf(var, 0.f)) + 1e-6f;

    float t   = (avg[(size_t)bo * HW + pos] - m) / sd * aw[oc] + ab[oc];
    float sig = 1.f / (1.f + __expf(-t));

    const float* sb = sIn + (size_t)bo * 16 * HW + pos;
    const float* xb = x   + (size_t)bo * 16 * HW + pos;   // bo*16 = b*128 + oc*16: matches x channel layout
    float* ob = out + (size_t)bo * 16 * HW + pos;
#pragma unroll
    for (int od = 0; od < 16; ++od) ob[od * HW] = fmaf(sb[od * HW], sig, xb[od * HW]);
}

extern "C" void kernel_launch(void* const* d_in, const int* in_sizes, int n_in,
                              void* d_out, int out_size, void* d_ws, size_t ws_size,
                              hipStream_t stream) {
    const float* x  = (const float*)d_in[0];
    const float* w1 = (const float*)d_in[1];
    const float* b1 = (const float*)d_in[2];
    const float* w2 = (const float*)d_in[3];
    const float* b2 = (const float*)d_in[4];
    const float* w3 = (const float*)d_in[5];
    const float* b3 = (const float*)d_in[6];
    const float* aw = (const float*)d_in[7];
    const float* ab = (const float*)d_in[8];

    float* ws      = (float*)d_ws;
    float* h1      = ws;                     // 8*256*4096  = 8388608
    float* h2      = h1 + 8388608;           // 8388608
    float* sbuf    = h2 + 8388608;           // 8*8*16*4096 = 4194304
    float* avg     = sbuf + 4194304;         // 262144
    float* meanAcc = avg + 262144;           // 1024
    float* stats   = meanAcc + 1024;         // 128
    float* w2t     = stats + 128;            // 73728
    ushort* w3h    = (ushort*)(w2t + 73728); // 32768 halfs = 16384 floats

    hipMemsetAsync(meanAcc, 0, (1024 + 128) * sizeof(float), stream);
    k0_wt   <<<288, 256, 0, stream>>>(w2, w2t);
    k0b_w3h <<<128, 256, 0, stream>>>(w3, w3h);
    k1_conv1<<<1024, 256, 0, stream>>>(x, w1, b1, h1);
    k2_conv2<<<2048, 256, 0, stream>>>(h1, w2t, b2, h2);
    k3_route<<<1024, 256, 0, stream>>>(h2, w3h, b3, sbuf, meanAcc);
    k4_avg  <<<1024, 256, 0, stream>>>(sbuf, meanAcc, avg, stats);
    k5_out  <<<1024, 256, 0, stream>>>(sbuf, x, avg, stats, aw, ab, (float*)d_out);
}

// Round 5
// 251.375 us; speedup vs baseline: 1.0966x; 1.0757x over previous
//
#include <hip/hip_runtime.h>
#include <hip/hip_bf16.h>
#include <hip/hip_fp16.h>

#define HW 4096

typedef _Float16 f16x8 __attribute__((ext_vector_type(8)));
typedef float f32x4 __attribute__((ext_vector_type(4)));

static __device__ __forceinline__ __half2 u2h(unsigned int u) {
    union { unsigned int u; __half2 h; } c; c.u = u; return c.h;
}
static __device__ __forceinline__ unsigned int h2u(__half2 h) {
    union { unsigned int u; __half2 h; } c; c.h = h; return c.u;
}

// ---------------- K0: transpose w2 (IC*MID, MID, 3,3) -> w2t[g][ci*9+k][co] ----------------
__global__ __launch_bounds__(256) void k0_wt(const float* __restrict__ w2, float* __restrict__ w2t) {
    int idx = blockIdx.x * 256 + threadIdx.x;      // 8 * 9216 = 73728
    if (idx >= 8 * 9216) return;
    int g = idx / 9216;
    int r = idx % 9216;
    int co = r & 31;
    int t  = r >> 5;                                // ci*9 + ky*3 + kx
    w2t[idx] = w2[(size_t)(g * 32 + co) * 288 + t];
}

// ---------------- K0b: w3 -> fp16 MFMA A-fragment order ----------------
// w3h[p=(ic*8+oc)][lane][j] = fp16( w3[(ic*128+oc*16+od)*32 + m] ),
// od = lane&15, m = (lane>>4)*8 + j   (A-frag layout for mfma 16x16x32, HW-verified R4)
__global__ __launch_bounds__(256) void k0b_w3h(const float* __restrict__ w3, ushort* __restrict__ w3h) {
    int gi = blockIdx.x * 256 + threadIdx.x;       // 64*64*8 = 32768
    if (gi >= 32768) return;
    int j = gi & 7;
    int l = (gi >> 3) & 63;
    int p = gi >> 9;                                // ic*8+oc
    int ic = p >> 3, oc = p & 7;
    int od = l & 15;
    int m  = ((l >> 4) << 3) + j;
    __half h = __float2half(w3[(size_t)((ic * 128 + oc * 16 + od) * 32 + m)]);
    w3h[gi] = __half_as_ushort(h);
}

// ---------------- K1: relu(x) -> 1x1 conv (16->32 per group) -> relu -> h1 (fp16 NCHW) ----------------
__global__ __launch_bounds__(256) void k1_conv1(const float* __restrict__ x, const float* __restrict__ w1,
                                                const float* __restrict__ b1, __half* __restrict__ h1) {
    int bi = blockIdx.x;                 // ((b*8 + g)*16 + chunk)
    int chunk = bi & 15;
    int g = (bi >> 4) & 7;
    int b = bi >> 7;
    int pos = chunk * 256 + threadIdx.x;

    const float* xb = x + (size_t)(b * 128 + g * 16) * HW + pos;
    float xv[16];
#pragma unroll
    for (int i = 0; i < 16; ++i) xv[i] = fmaxf(xb[i * HW], 0.f);

    const float* wg = w1 + g * 32 * 16;  // uniform across block -> scalar loads
    const float* bg = b1 + g * 32;
    __half* hb = h1 + (size_t)(b * 256 + g * 32) * HW + pos;
#pragma unroll
    for (int m = 0; m < 32; ++m) {
        float acc = bg[m];
#pragma unroll
        for (int i = 0; i < 16; ++i) acc = fmaf(xv[i], wg[m * 16 + i], acc);
        hb[m * HW] = __float2half(fmaxf(acc, 0.f));
    }
}

// ---------------- K2: grouped 3x3 SAME conv (32->32) + relu -> h2g fp16 [b][g][px][32] ----------------
__global__ __launch_bounds__(256) void k2_conv2(const __half* __restrict__ h1, const float* __restrict__ w2t,
                                                const float* __restrict__ b2, ushort* __restrict__ h2g) {
    __shared__ float in_s[32][6][35];   // 32 ci x 6 rows x (34 cols, pad to 35)
    __shared__ float w_s[9216];         // [ci*9+k][co]

    int bi = blockIdx.x;                // b*256 + g*32 + rt*2 + ct
    int ct = bi & 1;
    int rt = (bi >> 1) & 15;
    int g  = (bi >> 5) & 7;
    int b  = bi >> 8;
    int y0 = rt * 4, x0 = ct * 32;
    int tid = threadIdx.x;

    const float* wg = w2t + g * 9216;
    for (int i = tid; i < 9216; i += 256) w_s[i] = wg[i];

    const __half* hb = h1 + (size_t)(b * 256 + g * 32) * HW;
    for (int i = tid; i < 32 * 6 * 34; i += 256) {
        int c  = i % 34;
        int r  = (i / 34) % 6;
        int ci = i / 204;
        int gy = y0 + r - 1, gx = x0 + c - 1;
        float v = 0.f;
        if (gy >= 0 && gy < 64 && gx >= 0 && gx < 64) v = __half2float(hb[ci * HW + gy * 64 + gx]);
        in_s[ci][r][c] = v;
    }
    __syncthreads();

    int cog  = tid >> 5;          // 0..7 -> co = cog*4 + j
    int posg = tid & 31;
    int r0 = posg >> 3;           // 0..3 output row in tile
    int c0 = (posg & 7) * 4;      // output col group

    float acc[4][4];
#pragma unroll
    for (int j = 0; j < 4; ++j) {
        float bb = b2[g * 32 + cog * 4 + j];
#pragma unroll
        for (int p = 0; p < 4; ++p) acc[j][p] = bb;
    }

    for (int ci = 0; ci < 32; ++ci) {
        float iv[3][6];
#pragma unroll
        for (int ky = 0; ky < 3; ++ky)
#pragma unroll
            for (int c = 0; c < 6; ++c) iv[ky][c] = in_s[ci][r0 + ky][c0 + c];
        const float* wc = &w_s[ci * 288];
#pragma unroll
        for (int ky = 0; ky < 3; ++ky)
#pragma unroll
            for (int kx = 0; kx < 3; ++kx) {
                const float4 wv = *reinterpret_cast<const float4*>(&wc[(ky * 3 + kx) * 32 + cog * 4]);
#pragma unroll
                for (int p = 0; p < 4; ++p) {
                    float in = iv[ky][kx + p];
                    acc[0][p] = fmaf(in, wv.x, acc[0][p]);
                    acc[1][p] = fmaf(in, wv.y, acc[1][p]);
                    acc[2][p] = fmaf(in, wv.z, acc[2][p]);
                    acc[3][p] = fmaf(in, wv.w, acc[3][p]);
                }
            }
    }

    // write [b][g][px][32ch] fp16: per px, 4 co = 8 B
    ushort* ob = h2g + (((size_t)(b * 8 + g) * HW) + (y0 + r0) * 64 + (x0 + c0)) * 32 + cog * 4;
#pragma unroll
    for (int p = 0; p < 4; ++p) {
        __half2 lo = __floats2half2_rn(fmaxf(acc[0][p], 0.f), fmaxf(acc[1][p], 0.f));
        __half2 hi = __floats2half2_rn(fmaxf(acc[2][p], 0.f), fmaxf(acc[3][p], 0.f));
        uint2 wv; wv.x = h2u(lo); wv.y = h2u(hi);
        *(uint2*)&ob[(size_t)p * 32] = wv;
    }
}

// ---------------- K3: conv3 via MFMA (fp16, B-frag direct from global) + routing ----------------
// 512 thr (8 waves), 32 px. LDS: u only (64 KB, XOR-swizzled) -> 2 blocks/CU = 16 waves/CU.
// Phase A: wave w = ic w; 8 oc pairs x 2 px-tiles; B-frag = one coalesced 16B load from h2g.
// Phase B: t<256, thread=(oc,px), u via ds_read_b128, routing all-in-register.
__global__ __launch_bounds__(512) void k3_route(const ushort* __restrict__ h2g, const ushort* __restrict__ w3h,
                                                const float* __restrict__ b3, float* __restrict__ sOut,
                                                float* __restrict__ meanAcc) {
    __shared__ ushort u_lds[32 * 1024]; // [px][ch ^ ((px&15)<<3)]

    int bid = blockIdx.x;
    int b   = bid >> 7;
    int px0 = (bid & 127) * 32;
    int t   = threadIdx.x;

    // ---- phase A ----
    {
        int w = t >> 6, l = t & 63;
        int lrow = l & 15, lk = l >> 4;
        int ic = w;
        f16x8 bf[2];
#pragma unroll
        for (int pxt = 0; pxt < 2; ++pxt) {
            const ushort* hp = h2g + (((size_t)(b * 8 + ic) * HW) + px0 + pxt * 16 + lrow) * 32 + lk * 8;
            bf[pxt] = *(const f16x8*)hp;
        }
#pragma unroll
        for (int oc = 0; oc < 8; ++oc) {
            int p = ic * 8 + oc;
            f16x8 af = *(const f16x8*)&w3h[(p * 64 + l) * 8];
            float4 bias = *(const float4*)(b3 + ic * 128 + oc * 16 + lk * 4);
            f32x4 c0;
            c0[0] = bias.x; c0[1] = bias.y; c0[2] = bias.z; c0[3] = bias.w;
#pragma unroll
            for (int pxt = 0; pxt < 2; ++pxt) {
                f32x4 d = __builtin_amdgcn_mfma_f32_16x16x32_f16(af, bf[pxt], c0, 0, 0, 0);
                int px = lrow + pxt * 16;
                int s = (px & 15) << 3;
                int ch = ic * 128 + oc * 16 + lk * 4;   // od = lk*4 + reg
                __half2 lo = __floats2half2_rn(d[0], d[1]);
                __half2 hi = __floats2half2_rn(d[2], d[3]);
                uint2 wv; wv.x = h2u(lo); wv.y = h2u(hi);
                *(uint2*)&u_lds[(px << 10) + (ch ^ s)] = wv;
            }
        }
    }
    __syncthreads();

    // ---- phase B: routing, t<256: thread = (oc = t>>5, px = t&31) ----
    if (t < 256) {
        int oc = t >> 5, px = t & 31;
        int s = (px & 15) << 3;
        const ushort* ur = &u_lds[px << 10];

        __half2 uh[8][8];
        float scale[8];
#pragma unroll
        for (int ic = 0; ic < 8; ++ic) {
            int ch = ic * 128 + oc * 16;
            uint4 ra = *(const uint4*)&ur[(ch + 0) ^ s];
            uint4 rb = *(const uint4*)&ur[(ch + 8) ^ s];
            uh[ic][0] = u2h(ra.x); uh[ic][1] = u2h(ra.y); uh[ic][2] = u2h(ra.z); uh[ic][3] = u2h(ra.w);
            uh[ic][4] = u2h(rb.x); uh[ic][5] = u2h(rb.y); uh[ic][6] = u2h(rb.z); uh[ic][7] = u2h(rb.w);
            float sq = 0.f;
#pragma unroll
            for (int j = 0; j < 8; ++j) {
                float2 f = __half22float2(uh[ic][j]);
                sq = fmaf(f.x, f.x, fmaf(f.y, f.y, sq));
            }
            scale[ic] = sq / ((0.5f + sq) * (sqrtf(sq + 1e-6f) + 1e-6f));
        }

        float br[8];
#pragma unroll
        for (int ic = 0; ic < 8; ++ic) br[ic] = 0.f;

#pragma unroll
        for (int it = 0; it < 2; ++it) {
            float csc[8];
#pragma unroll
            for (int ic = 0; ic < 8; ++ic) csc[ic] = scale[ic] / (1.f + __expf(-br[ic]));
            float sv[16];
            float sq = 0.f;
#pragma unroll
            for (int j = 0; j < 8; ++j) {
                float a0 = 0.f, a1 = 0.f;
#pragma unroll
                for (int ic = 0; ic < 8; ++ic) {
                    float2 f = __half22float2(uh[ic][j]);
                    a0 = fmaf(f.x, csc[ic], a0);
                    a1 = fmaf(f.y, csc[ic], a1);
                }
                sv[2 * j] = a0;
                sv[2 * j + 1] = a1;
                sq = fmaf(a0, a0, fmaf(a1, a1, sq));
            }
            float f = sq / ((0.5f + sq) * (sqrtf(sq + 1e-6f) + 1e-6f));
#pragma unroll
            for (int ic = 0; ic < 8; ++ic) {
                float d = 0.f;
#pragma unroll
                for (int j = 0; j < 8; ++j) {
                    float2 uf = __half22float2(uh[ic][j]);
                    d = fmaf(uf.x, sv[2 * j], fmaf(uf.y, sv[2 * j + 1], d));
                }
                br[ic] = fmaf(scale[ic] * f, d, br[ic]);
            }
        }

        float c_[8];
#pragma unroll
        for (int ic = 0; ic < 8; ++ic) c_[ic] = 1.f / (1.f + __expf(-br[ic]));

        float* sb = sOut + (size_t)((b * 8 + oc) * 16) * HW + px0 + px;
#pragma unroll
        for (int j = 0; j < 8; ++j) {
            float a0 = 0.f, a1 = 0.f;
#pragma unroll
            for (int ic = 0; ic < 8; ++ic) {
                float2 uf = __half22float2(uh[ic][j]);
                a0 = fmaf(uf.x, c_[ic], a0);
                a1 = fmaf(uf.y, c_[ic], a1);
            }
            sb[(2 * j) * HW] = a0;
            sb[(2 * j + 1) * HW] = a1;
            float r0 = a0, r1 = a1;
#pragma unroll
            for (int m = 1; m < 32; m <<= 1) {     // reduce over px (32 lanes per oc)
                r0 += __shfl_xor(r0, m);
                r1 += __shfl_xor(r1, m);
            }
            if ((t & 31) == 0) {
                atomicAdd(&meanAcc[(b * 8 + oc) * 16 + 2 * j], r0);
                atomicAdd(&meanAcc[(b * 8 + oc) * 16 + 2 * j + 1], r1);
            }
        }
    }
}

// ---------------- K4: avg = sum_od s*mean_hw; partial stats per (b,oc) ----------------
__global__ __launch_bounds__(256) void k4_avg(const float* __restrict__ sIn, const float* __restrict__ meanAcc,
                                              float* __restrict__ avg, float* __restrict__ stats) {
    int bi = blockIdx.x;                 // (b*8+oc)*16 + chunk
    int chunk = bi & 15;
    int bo = bi >> 4;
    int pos = chunk * 256 + threadIdx.x;

    const float* sb = sIn + (size_t)bo * 16 * HW + pos;
    const float* mh = meanAcc + bo * 16;
    float a = 0.f;
#pragma unroll
    for (int od = 0; od < 16; ++od) a = fmaf(sb[od * HW], mh[od] * (1.f / 4096.f), a);
    avg[(size_t)bo * HW + pos] = a;

    float s1 = a, s2 = a * a;
#pragma unroll
    for (int m = 1; m < 64; m <<= 1) {
        s1 += __shfl_xor(s1, m);
        s2 += __shfl_xor(s2, m);
    }
    if ((threadIdx.x & 63) == 0) {
        atomicAdd(&stats[bo * 2],     s1);
        atomicAdd(&stats[bo * 2 + 1], s2);
    }
}

// ---------------- K5: normalize, attn gate, residual ----------------
__global__ __launch_bounds__(256) void k5_out(const float* __restrict__ sIn, const float* __restrict__ x,
                                              const float* __restrict__ avg, const float* __restrict__ stats,
                                              const float* __restrict__ aw, const float* __restrict__ ab,
                                              float* __restrict__ out) {
    int bi = blockIdx.x;                 // (b*8+oc)*16 + chunk
    int chunk = bi & 15;
    int bo = bi >> 4;
    int oc = bo & 7;
    int pos = chunk * 256 + threadIdx.x;

    float sum = stats[bo * 2], sumsq = stats[bo * 2 + 1];
    float m   = sum * (1.f / 4096.f);
    float var = (sumsq - 4096.f * m * m) * (1.f / 4095.f);
    float sd  = sqrtf(fmaxf(var, 0.f)) + 1e-6f;

    float t   = (avg[(size_t)bo * HW + pos] - m) / sd * aw[oc] + ab[oc];
    float sig = 1.f / (1.f + __expf(-t));

    const float* sb = sIn + (size_t)bo * 16 * HW + pos;
    const float* xb = x   + (size_t)bo * 16 * HW + pos;   // bo*16 = b*128 + oc*16: matches x channel layout
    float* ob = out + (size_t)bo * 16 * HW + pos;
#pragma unroll
    for (int od = 0; od < 16; ++od) ob[od * HW] = fmaf(sb[od * HW], sig, xb[od * HW]);
}

extern "C" void kernel_launch(void* const* d_in, const int* in_sizes, int n_in,
                              void* d_out, int out_size, void* d_ws, size_t ws_size,
                              hipStream_t stream) {
    const float* x  = (const float*)d_in[0];
    const float* w1 = (const float*)d_in[1];
    const float* b1 = (const float*)d_in[2];
    const float* w2 = (const float*)d_in[3];
    const float* b2 = (const float*)d_in[4];
    const float* w3 = (const float*)d_in[5];
    const float* b3 = (const float*)d_in[6];
    const float* aw = (const float*)d_in[7];
    const float* ab = (const float*)d_in[8];

    float* ws      = (float*)d_ws;
    __half* h1h    = (__half*)ws;                    // 8,388,608 halfs  (4,194,304 floats)
    ushort* h2g    = (ushort*)(ws + 4194304);        // 8,388,608 halfs  (4,194,304 floats)
    float* sbuf    = ws + 8388608;                   // 4,194,304 floats
    float* avg     = sbuf + 4194304;                 // 262,144
    float* meanAcc = avg + 262144;                   // 1024
    float* stats   = meanAcc + 1024;                 // 128
    float* w2t     = stats + 128;                    // 73,728
    ushort* w3h    = (ushort*)(w2t + 73728);         // 32,768 halfs

    hipMemsetAsync(meanAcc, 0, (1024 + 128) * sizeof(float), stream);
    k0_wt   <<<288, 256, 0, stream>>>(w2, w2t);
    k0b_w3h <<<128, 256, 0, stream>>>(w3, w3h);
    k1_conv1<<<1024, 256, 0, stream>>>(x, w1, b1, h1h);
    k2_conv2<<<2048, 256, 0, stream>>>(h1h, w2t, b2, h2g);
    k3_route<<<1024, 512, 0, stream>>>(h2g, w3h, b3, sbuf, meanAcc);
    k4_avg  <<<1024, 256, 0, stream>>>(sbuf, meanAcc, avg, stats);
    k5_out  <<<1024, 256, 0, stream>>>(sbuf, x, avg, stats, aw, ab, (float*)d_out);
}

// Round 6
// 176.439 us; speedup vs baseline: 1.5624x; 1.4247x over previous
//
#include <hip/hip_runtime.h>
#include <hip/hip_bf16.h>
#include <hip/hip_fp16.h>

#define HW 4096

typedef _Float16 f16x8 __attribute__((ext_vector_type(8)));
typedef float f32x4 __attribute__((ext_vector_type(4)));

static __device__ __forceinline__ __half2 u2h(unsigned int u) {
    union { unsigned int u; __half2 h; } c; c.u = u; return c.h;
}
static __device__ __forceinline__ unsigned int h2u(__half2 h) {
    union { unsigned int u; __half2 h; } c; c.h = h; return c.u;
}
static __device__ __forceinline__ f16x8 uint4_as_f16x8(uint4 v) {
    union { uint4 u; f16x8 f; } c; c.u = v; return c.f;
}

// ---------------- K0b: w3 -> fp16 MFMA A-fragment order ----------------
// w3h[p=(ic*8+oc)][lane][j] = fp16( w3[(ic*128+oc*16+od)*32 + m] ),
// od = lane&15, m = (lane>>4)*8 + j   (A-frag layout for mfma 16x16x32, HW-verified R4)
__global__ __launch_bounds__(256) void k0b_w3h(const float* __restrict__ w3, ushort* __restrict__ w3h) {
    int gi = blockIdx.x * 256 + threadIdx.x;       // 64*64*8 = 32768
    if (gi >= 32768) return;
    int j = gi & 7;
    int l = (gi >> 3) & 63;
    int p = gi >> 9;                                // ic*8+oc
    int ic = p >> 3, oc = p & 7;
    int od = l & 15;
    int m  = ((l >> 4) << 3) + j;
    __half h = __float2half(w3[(size_t)((ic * 128 + oc * 16 + od) * 32 + m)]);
    w3h[gi] = __half_as_ushort(h);
}

// ---------------- K0c: w2 -> fp16 MFMA A-fragment order ----------------
// w2f[g][tap][h][lane][j] = fp16( w2[co=h*16+(l&15)][ci=(l>>4)*8+j][tap] )
__global__ __launch_bounds__(256) void k0c_w2f(const float* __restrict__ w2, ushort* __restrict__ w2f) {
    int gi = blockIdx.x * 256 + threadIdx.x;       // 8*9*2*64*8 = 73728
    if (gi >= 73728) return;
    int j   = gi & 7;
    int l   = (gi >> 3) & 63;
    int h   = (gi >> 9) & 1;
    int tap = (gi >> 10) % 9;
    int g   = gi / 9216;
    int co = h * 16 + (l & 15);
    int ci = ((l >> 4) << 3) + j;
    float v = w2[(size_t)((g * 32 + co) * 32 + ci) * 9 + tap];
    w2f[gi] = __half_as_ushort(__float2half(v));
}

// ---------------- K1: relu(x) -> 1x1 conv (16->32 per group) -> relu -> h1g fp16 [b][g][px][32] ----------------
__global__ __launch_bounds__(256) void k1_conv1(const float* __restrict__ x, const float* __restrict__ w1,
                                                const float* __restrict__ b1, ushort* __restrict__ h1g) {
    int bi = blockIdx.x;                 // ((b*8 + g)*16 + chunk)
    int chunk = bi & 15;
    int g = (bi >> 4) & 7;
    int b = bi >> 7;
    int pos = chunk * 256 + threadIdx.x;

    const float* xb = x + (size_t)(b * 128 + g * 16) * HW + pos;
    float xv[16];
#pragma unroll
    for (int i = 0; i < 16; ++i) xv[i] = fmaxf(xb[i * HW], 0.f);

    const float* wg = w1 + g * 32 * 16;  // uniform across block -> scalar loads
    const float* bg = b1 + g * 32;
    ushort hv[32];
#pragma unroll
    for (int m = 0; m < 32; ++m) {
        float acc = bg[m];
#pragma unroll
        for (int i = 0; i < 16; ++i) acc = fmaf(xv[i], wg[m * 16 + i], acc);
        hv[m] = __half_as_ushort(__float2half(fmaxf(acc, 0.f)));
    }
    ushort* hb = h1g + ((size_t)(b * 8 + g) * HW + pos) * 32;
#pragma unroll
    for (int q = 0; q < 4; ++q) *(uint4*)&hb[q * 8] = *(uint4*)&hv[q * 8];
}

// ---------------- K2: grouped 3x3 SAME conv via MFMA (9 shifted 1x1 GEMMs), no LDS ----------------
// Block 256 thr = 4 waves; wave = 16 px x 32 co of one (b,g). B-frag per tap = one
// clamped+masked 16B global load from h1g (y uniform per 16-px tile; x edges masked).
__global__ __launch_bounds__(256) void k2_conv2(const ushort* __restrict__ h1g, const ushort* __restrict__ w2f,
                                                const float* __restrict__ b2, ushort* __restrict__ h2g) {
    int bi = blockIdx.x;                 // b*512 + g*64 + pt
    int pt = bi & 63;
    int g  = (bi >> 6) & 7;
    int b  = bi >> 9;
    int t  = threadIdx.x;
    int w  = t >> 6, l = t & 63;
    int pxbase = pt * 64 + w * 16;       // multiple of 16 -> same image row
    int kgrp = l >> 4;

    int y = pxbase >> 6;
    int x = (pxbase & 63) + (l & 15);

    // ---- load 9 B-fragments (shifted inputs) ----
    const ushort* hbase = h1g + (size_t)(b * 8 + g) * HW * 32;
    f16x8 Bf[9];
#pragma unroll
    for (int dy = -1; dy <= 1; ++dy) {
        int yy = y + dy;
        int yyc = yy < 0 ? 0 : (yy > 63 ? 63 : yy);
        bool rv = (yy >= 0) && (yy < 64);
#pragma unroll
        for (int dx = -1; dx <= 1; ++dx) {
            int xx = x + dx;
            int xc = xx < 0 ? 0 : (xx > 63 ? 63 : xx);
            uint4 v = *(const uint4*)&hbase[((yyc << 6) + xc) * 32 + kgrp * 8];
            bool ok = rv && (xx >= 0) && (xx < 64);
            v.x = ok ? v.x : 0u; v.y = ok ? v.y : 0u;
            v.z = ok ? v.z : 0u; v.w = ok ? v.w : 0u;
            Bf[(dy + 1) * 3 + (dx + 1)] = uint4_as_f16x8(v);
        }
    }

    // ---- load 18 A-fragments (weights) ----
    const ushort* wg = w2f + (size_t)g * 9216;     // [tap][h][64][8]
    f16x8 Af[9][2];
#pragma unroll
    for (int tap = 0; tap < 9; ++tap)
#pragma unroll
        for (int h = 0; h < 2; ++h)
            Af[tap][h] = *(const f16x8*)&wg[((tap * 2 + h) * 64 + l) * 8];

    // ---- accumulate: acc[h] = bias; += A[tap][h] x B[tap] ----
    f32x4 acc[2];
#pragma unroll
    for (int h = 0; h < 2; ++h) {
        float4 bias = *(const float4*)(b2 + g * 32 + h * 16 + kgrp * 4);
        acc[h][0] = bias.x; acc[h][1] = bias.y; acc[h][2] = bias.z; acc[h][3] = bias.w;
    }
#pragma unroll
    for (int tap = 0; tap < 9; ++tap) {
#pragma unroll
        for (int h = 0; h < 2; ++h)
            acc[h] = __builtin_amdgcn_mfma_f32_16x16x32_f16(Af[tap][h], Bf[tap], acc[h], 0, 0, 0);
    }

    // ---- epilogue: relu, fp16 pack, store to h2g[b][g][px][32co] ----
    int px = pxbase + (l & 15);
    ushort* ob = h2g + ((size_t)(b * 8 + g) * HW + px) * 32;
#pragma unroll
    for (int h = 0; h < 2; ++h) {
        __half2 lo = __floats2half2_rn(fmaxf(acc[h][0], 0.f), fmaxf(acc[h][1], 0.f));
        __half2 hi = __floats2half2_rn(fmaxf(acc[h][2], 0.f), fmaxf(acc[h][3], 0.f));
        uint2 wv; wv.x = h2u(lo); wv.y = h2u(hi);
        *(uint2*)&ob[h * 16 + kgrp * 4] = wv;
    }
}

// ---------------- K3: conv3 via MFMA (fp16, B-frag direct from global) + routing ----------------
__global__ __launch_bounds__(512) void k3_route(const ushort* __restrict__ h2g, const ushort* __restrict__ w3h,
                                                const float* __restrict__ b3, float* __restrict__ sOut,
                                                float* __restrict__ meanAcc) {
    __shared__ ushort u_lds[32 * 1024]; // [px][ch ^ ((px&15)<<3)]

    int bid = blockIdx.x;
    int b   = bid >> 7;
    int px0 = (bid & 127) * 32;
    int t   = threadIdx.x;

    // ---- phase A ----
    {
        int w = t >> 6, l = t & 63;
        int lrow = l & 15, lk = l >> 4;
        int ic = w;
        f16x8 bf[2];
#pragma unroll
        for (int pxt = 0; pxt < 2; ++pxt) {
            const ushort* hp = h2g + (((size_t)(b * 8 + ic) * HW) + px0 + pxt * 16 + lrow) * 32 + lk * 8;
            bf[pxt] = *(const f16x8*)hp;
        }
#pragma unroll
        for (int oc = 0; oc < 8; ++oc) {
            int p = ic * 8 + oc;
            f16x8 af = *(const f16x8*)&w3h[(p * 64 + l) * 8];
            float4 bias = *(const float4*)(b3 + ic * 128 + oc * 16 + lk * 4);
            f32x4 c0;
            c0[0] = bias.x; c0[1] = bias.y; c0[2] = bias.z; c0[3] = bias.w;
#pragma unroll
            for (int pxt = 0; pxt < 2; ++pxt) {
                f32x4 d = __builtin_amdgcn_mfma_f32_16x16x32_f16(af, bf[pxt], c0, 0, 0, 0);
                int px = lrow + pxt * 16;
                int s = (px & 15) << 3;
                int ch = ic * 128 + oc * 16 + lk * 4;   // od = lk*4 + reg
                __half2 lo = __floats2half2_rn(d[0], d[1]);
                __half2 hi = __floats2half2_rn(d[2], d[3]);
                uint2 wv; wv.x = h2u(lo); wv.y = h2u(hi);
                *(uint2*)&u_lds[(px << 10) + (ch ^ s)] = wv;
            }
        }
    }
    __syncthreads();

    // ---- phase B: routing, t<256: thread = (oc = t>>5, px = t&31) ----
    if (t < 256) {
        int oc = t >> 5, px = t & 31;
        int s = (px & 15) << 3;
        const ushort* ur = &u_lds[px << 10];

        __half2 uh[8][8];
        float scale[8];
#pragma unroll
        for (int ic = 0; ic < 8; ++ic) {
            int ch = ic * 128 + oc * 16;
            uint4 ra = *(const uint4*)&ur[(ch + 0) ^ s];
            uint4 rb = *(const uint4*)&ur[(ch + 8) ^ s];
            uh[ic][0] = u2h(ra.x); uh[ic][1] = u2h(ra.y); uh[ic][2] = u2h(ra.z); uh[ic][3] = u2h(ra.w);
            uh[ic][4] = u2h(rb.x); uh[ic][5] = u2h(rb.y); uh[ic][6] = u2h(rb.z); uh[ic][7] = u2h(rb.w);
            float sq = 0.f;
#pragma unroll
            for (int j = 0; j < 8; ++j) {
                float2 f = __half22float2(uh[ic][j]);
                sq = fmaf(f.x, f.x, fmaf(f.y, f.y, sq));
            }
            scale[ic] = sq / ((0.5f + sq) * (sqrtf(sq + 1e-6f) + 1e-6f));
        }

        float br[8];
#pragma unroll
        for (int ic = 0; ic < 8; ++ic) br[ic] = 0.f;

#pragma unroll
        for (int it = 0; it < 2; ++it) {
            float csc[8];
#pragma unroll
            for (int ic = 0; ic < 8; ++ic) csc[ic] = scale[ic] / (1.f + __expf(-br[ic]));
            float sv[16];
            float sq = 0.f;
#pragma unroll
            for (int j = 0; j < 8; ++j) {
                float a0 = 0.f, a1 = 0.f;
#pragma unroll
                for (int ic = 0; ic < 8; ++ic) {
                    float2 f = __half22float2(uh[ic][j]);
                    a0 = fmaf(f.x, csc[ic], a0);
                    a1 = fmaf(f.y, csc[ic], a1);
                }
                sv[2 * j] = a0;
                sv[2 * j + 1] = a1;
                sq = fmaf(a0, a0, fmaf(a1, a1, sq));
            }
            float f = sq / ((0.5f + sq) * (sqrtf(sq + 1e-6f) + 1e-6f));
#pragma unroll
            for (int ic = 0; ic < 8; ++ic) {
                float d = 0.f;
#pragma unroll
                for (int j = 0; j < 8; ++j) {
                    float2 uf = __half22float2(uh[ic][j]);
                    d = fmaf(uf.x, sv[2 * j], fmaf(uf.y, sv[2 * j + 1], d));
                }
                br[ic] = fmaf(scale[ic] * f, d, br[ic]);
            }
        }

        float c_[8];
#pragma unroll
        for (int ic = 0; ic < 8; ++ic) c_[ic] = 1.f / (1.f + __expf(-br[ic]));

        float* sb = sOut + (size_t)((b * 8 + oc) * 16) * HW + px0 + px;
#pragma unroll
        for (int j = 0; j < 8; ++j) {
            float a0 = 0.f, a1 = 0.f;
#pragma unroll
            for (int ic = 0; ic < 8; ++ic) {
                float2 uf = __half22float2(uh[ic][j]);
                a0 = fmaf(uf.x, c_[ic], a0);
                a1 = fmaf(uf.y, c_[ic], a1);
            }
            sb[(2 * j) * HW] = a0;
            sb[(2 * j + 1) * HW] = a1;
            float r0 = a0, r1 = a1;
#pragma unroll
            for (int m = 1; m < 32; m <<= 1) {     // reduce over px (32 lanes per oc)
                r0 += __shfl_xor(r0, m);
                r1 += __shfl_xor(r1, m);
            }
            if ((t & 31) == 0) {
                atomicAdd(&meanAcc[(b * 8 + oc) * 16 + 2 * j], r0);
                atomicAdd(&meanAcc[(b * 8 + oc) * 16 + 2 * j + 1], r1);
            }
        }
    }
}

// ---------------- K4: avg = sum_od s*mean_hw; partial stats per (b,oc) ----------------
__global__ __launch_bounds__(256) void k4_avg(const float* __restrict__ sIn, const float* __restrict__ meanAcc,
                                              float* __restrict__ avg, float* __restrict__ stats) {
    int bi = blockIdx.x;                 // (b*8+oc)*16 + chunk
    int chunk = bi & 15;
    int bo = bi >> 4;
    int pos = chunk * 256 + threadIdx.x;

    const float* sb = sIn + (size_t)bo * 16 * HW + pos;
    const float* mh = meanAcc + bo * 16;
    float a = 0.f;
#pragma unroll
    for (int od = 0; od < 16; ++od) a = fmaf(sb[od * HW], mh[od] * (1.f / 4096.f), a);
    avg[(size_t)bo * HW + pos] = a;

    float s1 = a, s2 = a * a;
#pragma unroll
    for (int m = 1; m < 64; m <<= 1) {
        s1 += __shfl_xor(s1, m);
        s2 += __shfl_xor(s2, m);
    }
    if ((threadIdx.x & 63) == 0) {
        atomicAdd(&stats[bo * 2],     s1);
        atomicAdd(&stats[bo * 2 + 1], s2);
    }
}

// ---------------- K5: normalize, attn gate, residual ----------------
__global__ __launch_bounds__(256) void k5_out(const float* __restrict__ sIn, const float* __restrict__ x,
                                              const float* __restrict__ avg, const float* __restrict__ stats,
                                              const float* __restrict__ aw, const float* __restrict__ ab,
                                              float* __restrict__ out) {
    int bi = blockIdx.x;                 // (b*8+oc)*16 + chunk
    int chunk = bi & 15;
    int bo = bi >> 4;
    int oc = bo & 7;
    int pos = chunk * 256 + threadIdx.x;

    float sum = stats[bo * 2], sumsq = stats[bo * 2 + 1];
    float m   = sum * (1.f / 4096.f);
    float var = (sumsq - 4096.f * m * m) * (1.f / 4095.f);
    float sd  = sqrtf(fmaxf(var, 0.f)) + 1e-6f;

    float t   = (avg[(size_t)bo * HW + pos] - m) / sd * aw[oc] + ab[oc];
    float sig = 1.f / (1.f + __expf(-t));

    const float* sb = sIn + (size_t)bo * 16 * HW + pos;
    const float* xb = x   + (size_t)bo * 16 * HW + pos;   // bo*16 = b*128 + oc*16: matches x channel layout
    float* ob = out + (size_t)bo * 16 * HW + pos;
#pragma unroll
    for (int od = 0; od < 16; ++od) ob[od * HW] = fmaf(sb[od * HW], sig, xb[od * HW]);
}

extern "C" void kernel_launch(void* const* d_in, const int* in_sizes, int n_in,
                              void* d_out, int out_size, void* d_ws, size_t ws_size,
                              hipStream_t stream) {
    const float* x  = (const float*)d_in[0];
    const float* w1 = (const float*)d_in[1];
    const float* b1 = (const float*)d_in[2];
    const float* w2 = (const float*)d_in[3];
    const float* b2 = (const float*)d_in[4];
    const float* w3 = (const float*)d_in[5];
    const float* b3 = (const float*)d_in[6];
    const float* aw = (const float*)d_in[7];
    const float* ab = (const float*)d_in[8];

    float* ws      = (float*)d_ws;
    ushort* h1g    = (ushort*)ws;                    // 8,388,608 halfs  (4,194,304 floats)
    ushort* h2g    = (ushort*)(ws + 4194304);        // 8,388,608 halfs
    float* sbuf    = ws + 8388608;                   // 4,194,304 floats
    float* avg     = sbuf + 4194304;                 // 262,144
    float* meanAcc = avg + 262144;                   // 1024
    float* stats   = meanAcc + 1024;                 // 128
    ushort* w3h    = (ushort*)(stats + 128);         // 32,768 halfs = 16,384 floats
    ushort* w2f    = (ushort*)(stats + 128 + 16384); // 73,728 halfs = 36,864 floats

    hipMemsetAsync(meanAcc, 0, (1024 + 128) * sizeof(float), stream);
    k0b_w3h <<<128, 256, 0, stream>>>(w3, w3h);
    k0c_w2f <<<288, 256, 0, stream>>>(w2, w2f);
    k1_conv1<<<1024, 256, 0, stream>>>(x, w1, b1, h1g);
    k2_conv2<<<4096, 256, 0, stream>>>(h1g, w2f, b2, h2g);
    k3_route<<<1024, 512, 0, stream>>>(h2g, w3h, b3, sbuf, meanAcc);
    k4_avg  <<<1024, 256, 0, stream>>>(sbuf, meanAcc, avg, stats);
    k5_out  <<<1024, 256, 0, stream>>>(sbuf, x, avg, stats, aw, ab, (float*)d_out);
}

// Round 7
// 143.683 us; speedup vs baseline: 1.9186x; 1.2280x over previous
//
#include <hip/hip_runtime.h>
#include <hip/hip_bf16.h>
#include <hip/hip_fp16.h>

#define HW 4096

typedef _Float16 f16x8 __attribute__((ext_vector_type(8)));
typedef float f32x4 __attribute__((ext_vector_type(4)));

static __device__ __forceinline__ __half2 u2h(unsigned int u) {
    union { unsigned int u; __half2 h; } c; c.u = u; return c.h;
}
static __device__ __forceinline__ unsigned int h2u(__half2 h) {
    union { unsigned int u; __half2 h; } c; c.h = h; return c.u;
}
static __device__ __forceinline__ f16x8 uint4_as_f16x8(uint4 v) {
    union { uint4 u; f16x8 f; } c; c.u = v; return c.f;
}

// ---------------- K0b: w3 -> fp16 MFMA A-fragment order ----------------
// w3h[p=(ic*8+oc)][lane][j] = fp16( w3[(ic*128+oc*16+od)*32 + m] ),
// od = lane&15, m = (lane>>4)*8 + j   (A-frag layout for mfma 16x16x32, HW-verified R4)
__global__ __launch_bounds__(256) void k0b_w3h(const float* __restrict__ w3, ushort* __restrict__ w3h) {
    int gi = blockIdx.x * 256 + threadIdx.x;       // 64*64*8 = 32768
    if (gi >= 32768) return;
    int j = gi & 7;
    int l = (gi >> 3) & 63;
    int p = gi >> 9;                                // ic*8+oc
    int ic = p >> 3, oc = p & 7;
    int od = l & 15;
    int m  = ((l >> 4) << 3) + j;
    __half h = __float2half(w3[(size_t)((ic * 128 + oc * 16 + od) * 32 + m)]);
    w3h[gi] = __half_as_ushort(h);
}

// ---------------- K0c: w2 -> fp16 MFMA A-fragment order ----------------
// w2f[g][tap][h][lane][j] = fp16( w2[co=h*16+(l&15)][ci=(l>>4)*8+j][tap] )
__global__ __launch_bounds__(256) void k0c_w2f(const float* __restrict__ w2, ushort* __restrict__ w2f) {
    int gi = blockIdx.x * 256 + threadIdx.x;       // 8*9*2*64*8 = 73728
    if (gi >= 73728) return;
    int j   = gi & 7;
    int l   = (gi >> 3) & 63;
    int h   = (gi >> 9) & 1;
    int tap = (gi >> 10) % 9;
    int g   = gi / 9216;
    int co = h * 16 + (l & 15);
    int ci = ((l >> 4) << 3) + j;
    float v = w2[(size_t)((g * 32 + co) * 32 + ci) * 9 + tap];
    w2f[gi] = __half_as_ushort(__float2half(v));
}

// ---------------- K1: relu(x) -> 1x1 conv (16->32 per group) -> relu -> h1g fp16 [b][g][px][32] ----------------
__global__ __launch_bounds__(256) void k1_conv1(const float* __restrict__ x, const float* __restrict__ w1,
                                                const float* __restrict__ b1, ushort* __restrict__ h1g) {
    int bi = blockIdx.x;                 // ((b*8 + g)*16 + chunk)
    int chunk = bi & 15;
    int g = (bi >> 4) & 7;
    int b = bi >> 7;
    int pos = chunk * 256 + threadIdx.x;

    const float* xb = x + (size_t)(b * 128 + g * 16) * HW + pos;
    float xv[16];
#pragma unroll
    for (int i = 0; i < 16; ++i) xv[i] = fmaxf(xb[i * HW], 0.f);

    const float* wg = w1 + g * 32 * 16;  // uniform across block -> scalar loads
    const float* bg = b1 + g * 32;
    ushort hv[32];
#pragma unroll
    for (int m = 0; m < 32; ++m) {
        float acc = bg[m];
#pragma unroll
        for (int i = 0; i < 16; ++i) acc = fmaf(xv[i], wg[m * 16 + i], acc);
        hv[m] = __half_as_ushort(__float2half(fmaxf(acc, 0.f)));
    }
    ushort* hb = h1g + ((size_t)(b * 8 + g) * HW + pos) * 32;
#pragma unroll
    for (int q = 0; q < 4; ++q) *(uint4*)&hb[q * 8] = *(uint4*)&hv[q * 8];
}

// ---------------- K2: grouped 3x3 SAME conv via MFMA (9 shifted 1x1 GEMMs), no LDS ----------------
__global__ __launch_bounds__(256) void k2_conv2(const ushort* __restrict__ h1g, const ushort* __restrict__ w2f,
                                                const float* __restrict__ b2, ushort* __restrict__ h2g) {
    int bi = blockIdx.x;                 // b*512 + g*64 + pt
    int pt = bi & 63;
    int g  = (bi >> 6) & 7;
    int b  = bi >> 9;
    int t  = threadIdx.x;
    int w  = t >> 6, l = t & 63;
    int pxbase = pt * 64 + w * 16;       // multiple of 16 -> same image row
    int kgrp = l >> 4;

    int y = pxbase >> 6;
    int x = (pxbase & 63) + (l & 15);

    // ---- load 9 B-fragments (shifted inputs) ----
    const ushort* hbase = h1g + (size_t)(b * 8 + g) * HW * 32;
    f16x8 Bf[9];
#pragma unroll
    for (int dy = -1; dy <= 1; ++dy) {
        int yy = y + dy;
        int yyc = yy < 0 ? 0 : (yy > 63 ? 63 : yy);
        bool rv = (yy >= 0) && (yy < 64);
#pragma unroll
        for (int dx = -1; dx <= 1; ++dx) {
            int xx = x + dx;
            int xc = xx < 0 ? 0 : (xx > 63 ? 63 : xx);
            uint4 v = *(const uint4*)&hbase[((yyc << 6) + xc) * 32 + kgrp * 8];
            bool ok = rv && (xx >= 0) && (xx < 64);
            v.x = ok ? v.x : 0u; v.y = ok ? v.y : 0u;
            v.z = ok ? v.z : 0u; v.w = ok ? v.w : 0u;
            Bf[(dy + 1) * 3 + (dx + 1)] = uint4_as_f16x8(v);
        }
    }

    // ---- load 18 A-fragments (weights) ----
    const ushort* wg = w2f + (size_t)g * 9216;     // [tap][h][64][8]
    f16x8 Af[9][2];
#pragma unroll
    for (int tap = 0; tap < 9; ++tap)
#pragma unroll
        for (int h = 0; h < 2; ++h)
            Af[tap][h] = *(const f16x8*)&wg[((tap * 2 + h) * 64 + l) * 8];

    // ---- accumulate ----
    f32x4 acc[2];
#pragma unroll
    for (int h = 0; h < 2; ++h) {
        float4 bias = *(const float4*)(b2 + g * 32 + h * 16 + kgrp * 4);
        acc[h][0] = bias.x; acc[h][1] = bias.y; acc[h][2] = bias.z; acc[h][3] = bias.w;
    }
#pragma unroll
    for (int tap = 0; tap < 9; ++tap) {
#pragma unroll
        for (int h = 0; h < 2; ++h)
            acc[h] = __builtin_amdgcn_mfma_f32_16x16x32_f16(Af[tap][h], Bf[tap], acc[h], 0, 0, 0);
    }

    // ---- epilogue: relu, fp16 pack, store to h2g[b][g][px][32co] ----
    int px = pxbase + (l & 15);
    ushort* ob = h2g + ((size_t)(b * 8 + g) * HW + px) * 32;
#pragma unroll
    for (int h = 0; h < 2; ++h) {
        __half2 lo = __floats2half2_rn(fmaxf(acc[h][0], 0.f), fmaxf(acc[h][1], 0.f));
        __half2 hi = __floats2half2_rn(fmaxf(acc[h][2], 0.f), fmaxf(acc[h][3], 0.f));
        uint2 wv; wv.x = h2u(lo); wv.y = h2u(hi);
        *(uint2*)&ob[h * 16 + kgrp * 4] = wv;
    }
}

// ---------------- K3: conv3 via MFMA + routing; phase B od-split across wave halves ----------------
// 512 thr (8 waves), 32 px, LDS u only (64 KB -> 2 blocks/CU = 4 waves/EU).
// Phase B: thread = (oc = wave, px = lane&31, odh = lane>>5); uh[8][4] half2 = 32 VGPRs;
// od-reductions = partial + one __shfl_xor(.,32). Peak liveness ~85 regs -> no spill.
__global__ __attribute__((amdgpu_flat_work_group_size(512, 512), amdgpu_waves_per_eu(4, 4)))
void k3_route(const ushort* __restrict__ h2g, const ushort* __restrict__ w3h,
              const float* __restrict__ b3, float* __restrict__ sOut,
              float* __restrict__ meanAcc) {
    __shared__ ushort u_lds[32 * 1024]; // [px][ch ^ ((px&15)<<3)]

    int bid = blockIdx.x;
    int b   = bid >> 7;
    int px0 = (bid & 127) * 32;
    int t   = threadIdx.x;
    int w   = t >> 6, l = t & 63;

    // ---- phase A: conv3 MFMA, wave = ic ----
    {
        int lrow = l & 15, lk = l >> 4;
        int ic = w;
        f16x8 bf[2];
#pragma unroll
        for (int pxt = 0; pxt < 2; ++pxt) {
            const ushort* hp = h2g + (((size_t)(b * 8 + ic) * HW) + px0 + pxt * 16 + lrow) * 32 + lk * 8;
            bf[pxt] = *(const f16x8*)hp;
        }
#pragma unroll
        for (int oc = 0; oc < 8; ++oc) {
            int p = ic * 8 + oc;
            f16x8 af = *(const f16x8*)&w3h[(p * 64 + l) * 8];
            float4 bias = *(const float4*)(b3 + ic * 128 + oc * 16 + lk * 4);
            f32x4 c0;
            c0[0] = bias.x; c0[1] = bias.y; c0[2] = bias.z; c0[3] = bias.w;
#pragma unroll
            for (int pxt = 0; pxt < 2; ++pxt) {
                f32x4 d = __builtin_amdgcn_mfma_f32_16x16x32_f16(af, bf[pxt], c0, 0, 0, 0);
                int px = lrow + pxt * 16;
                int s = (px & 15) << 3;
                int ch = ic * 128 + oc * 16 + lk * 4;   // od = lk*4 + reg
                __half2 lo = __floats2half2_rn(d[0], d[1]);
                __half2 hi = __floats2half2_rn(d[2], d[3]);
                uint2 wv; wv.x = h2u(lo); wv.y = h2u(hi);
                *(uint2*)&u_lds[(px << 10) + (ch ^ s)] = wv;
            }
        }
    }
    __syncthreads();

    // ---- phase B: routing; oc = wave, px = l&31, odh = l>>5 ----
    {
        int oc = w, px = l & 31, odh = l >> 5;
        int s = (px & 15) << 3;
        const ushort* ur = &u_lds[px << 10];

        __half2 uh[8][4];                 // od = odh*8 + 2j, 2j+1
        float scale[8];
#pragma unroll
        for (int ic = 0; ic < 8; ++ic) {
            int ch = ic * 128 + oc * 16 + odh * 8;
            uint4 ra = *(const uint4*)&ur[ch ^ s];
            uh[ic][0] = u2h(ra.x); uh[ic][1] = u2h(ra.y);
            uh[ic][2] = u2h(ra.z); uh[ic][3] = u2h(ra.w);
            float sqp = 0.f;
#pragma unroll
            for (int j = 0; j < 4; ++j) {
                float2 f = __half22float2(uh[ic][j]);
                sqp = fmaf(f.x, f.x, fmaf(f.y, f.y, sqp));
            }
            float sq = sqp + __shfl_xor(sqp, 32);
            scale[ic] = sq / ((0.5f + sq) * (sqrtf(sq + 1e-6f) + 1e-6f));
        }

        float br[8];
#pragma unroll
        for (int ic = 0; ic < 8; ++ic) br[ic] = 0.f;

#pragma unroll
        for (int it = 0; it < 2; ++it) {
            float csc[8];
#pragma unroll
            for (int ic = 0; ic < 8; ++ic) csc[ic] = scale[ic] / (1.f + __expf(-br[ic]));
            float sv[8];                  // own half's 8 od values of s
            float sqp = 0.f;
#pragma unroll
            for (int j = 0; j < 4; ++j) {
                float a0 = 0.f, a1 = 0.f;
#pragma unroll
                for (int ic = 0; ic < 8; ++ic) {
                    float2 f = __half22float2(uh[ic][j]);
                    a0 = fmaf(f.x, csc[ic], a0);
                    a1 = fmaf(f.y, csc[ic], a1);
                }
                sv[2 * j] = a0;
                sv[2 * j + 1] = a1;
                sqp = fmaf(a0, a0, fmaf(a1, a1, sqp));
            }
            float sq = sqp + __shfl_xor(sqp, 32);
            float f = sq / ((0.5f + sq) * (sqrtf(sq + 1e-6f) + 1e-6f));
#pragma unroll
            for (int ic = 0; ic < 8; ++ic) {
                float dp = 0.f;
#pragma unroll
                for (int j = 0; j < 4; ++j) {
                    float2 uf = __half22float2(uh[ic][j]);
                    dp = fmaf(uf.x, sv[2 * j], fmaf(uf.y, sv[2 * j + 1], dp));
                }
                float d = dp + __shfl_xor(dp, 32);
                br[ic] = fmaf(scale[ic] * f, d, br[ic]);
            }
        }

        float c_[8];
#pragma unroll
        for (int ic = 0; ic < 8; ++ic) c_[ic] = 1.f / (1.f + __expf(-br[ic]));

        float* sb = sOut + (size_t)((b * 8 + oc) * 16 + odh * 8) * HW + px0 + px;
#pragma unroll
        for (int j = 0; j < 4; ++j) {
            float a0 = 0.f, a1 = 0.f;
#pragma unroll
            for (int ic = 0; ic < 8; ++ic) {
                float2 uf = __half22float2(uh[ic][j]);
                a0 = fmaf(uf.x, c_[ic], a0);
                a1 = fmaf(uf.y, c_[ic], a1);
            }
            sb[(2 * j) * HW] = a0;
            sb[(2 * j + 1) * HW] = a1;
            float r0 = a0, r1 = a1;
#pragma unroll
            for (int m = 1; m < 32; m <<= 1) {     // reduce over px within this 32-lane half
                r0 += __shfl_xor(r0, m);
                r1 += __shfl_xor(r1, m);
            }
            if ((l & 31) == 0) {
                atomicAdd(&meanAcc[(b * 8 + oc) * 16 + odh * 8 + 2 * j], r0);
                atomicAdd(&meanAcc[(b * 8 + oc) * 16 + odh * 8 + 2 * j + 1], r1);
            }
        }
    }
}

// ---------------- K4: avg = sum_od s*mean_hw; partial stats per (b,oc) ----------------
__global__ __launch_bounds__(256) void k4_avg(const float* __restrict__ sIn, const float* __restrict__ meanAcc,
                                              float* __restrict__ avg, float* __restrict__ stats) {
    int bi = blockIdx.x;                 // (b*8+oc)*16 + chunk
    int chunk = bi & 15;
    int bo = bi >> 4;
    int pos = chunk * 256 + threadIdx.x;

    const float* sb = sIn + (size_t)bo * 16 * HW + pos;
    const float* mh = meanAcc + bo * 16;
    float a = 0.f;
#pragma unroll
    for (int od = 0; od < 16; ++od) a = fmaf(sb[od * HW], mh[od] * (1.f / 4096.f), a);
    avg[(size_t)bo * HW + pos] = a;

    float s1 = a, s2 = a * a;
#pragma unroll
    for (int m = 1; m < 64; m <<= 1) {
        s1 += __shfl_xor(s1, m);
        s2 += __shfl_xor(s2, m);
    }
    if ((threadIdx.x & 63) == 0) {
        atomicAdd(&stats[bo * 2],     s1);
        atomicAdd(&stats[bo * 2 + 1], s2);
    }
}

// ---------------- K5: normalize, attn gate, residual ----------------
__global__ __launch_bounds__(256) void k5_out(const float* __restrict__ sIn, const float* __restrict__ x,
                                              const float* __restrict__ avg, const float* __restrict__ stats,
                                              const float* __restrict__ aw, const float* __restrict__ ab,
                                              float* __restrict__ out) {
    int bi = blockIdx.x;                 // (b*8+oc)*16 + chunk
    int chunk = bi & 15;
    int bo = bi >> 4;
    int oc = bo & 7;
    int pos = chunk * 256 + threadIdx.x;

    float sum = stats[bo * 2], sumsq = stats[bo * 2 + 1];
    float m   = sum * (1.f / 4096.f);
    float var = (sumsq - 4096.f * m * m) * (1.f / 4095.f);
    float sd  = sqrtf(fmaxf(var, 0.f)) + 1e-6f;

    float t   = (avg[(size_t)bo * HW + pos] - m) / sd * aw[oc] + ab[oc];
    float sig = 1.f / (1.f + __expf(-t));

    const float* sb = sIn + (size_t)bo * 16 * HW + pos;
    const float* xb = x   + (size_t)bo * 16 * HW + pos;   // bo*16 = b*128 + oc*16: matches x channel layout
    float* ob = out + (size_t)bo * 16 * HW + pos;
#pragma unroll
    for (int od = 0; od < 16; ++od) ob[od * HW] = fmaf(sb[od * HW], sig, xb[od * HW]);
}

extern "C" void kernel_launch(void* const* d_in, const int* in_sizes, int n_in,
                              void* d_out, int out_size, void* d_ws, size_t ws_size,
                              hipStream_t stream) {
    const float* x  = (const float*)d_in[0];
    const float* w1 = (const float*)d_in[1];
    const float* b1 = (const float*)d_in[2];
    const float* w2 = (const float*)d_in[3];
    const float* b2 = (const float*)d_in[4];
    const float* w3 = (const float*)d_in[5];
    const float* b3 = (const float*)d_in[6];
    const float* aw = (const float*)d_in[7];
    const float* ab = (const float*)d_in[8];

    float* ws      = (float*)d_ws;
    ushort* h1g    = (ushort*)ws;                    // 8,388,608 halfs  (4,194,304 floats)
    ushort* h2g    = (ushort*)(ws + 4194304);        // 8,388,608 halfs
    float* sbuf    = ws + 8388608;                   // 4,194,304 floats
    float* avg     = sbuf + 4194304;                 // 262,144
    float* meanAcc = avg + 262144;                   // 1024
    float* stats   = meanAcc + 1024;                 // 128
    ushort* w3h    = (ushort*)(stats + 128);         // 32,768 halfs = 16,384 floats
    ushort* w2f    = (ushort*)(stats + 128 + 16384); // 73,728 halfs = 36,864 floats

    hipMemsetAsync(meanAcc, 0, (1024 + 128) * sizeof(float), stream);
    k0b_w3h <<<128, 256, 0, stream>>>(w3, w3h);
    k0c_w2f <<<288, 256, 0, stream>>>(w2, w2f);
    k1_conv1<<<1024, 256, 0, stream>>>(x, w1, b1, h1g);
    k2_conv2<<<4096, 256, 0, stream>>>(h1g, w2f, b2, h2g);
    k3_route<<<1024, 512, 0, stream>>>(h2g, w3h, b3, sbuf, meanAcc);
    k4_avg  <<<1024, 256, 0, stream>>>(sbuf, meanAcc, avg, stats);
    k5_out  <<<1024, 256, 0, stream>>>(sbuf, x, avg, stats, aw, ab, (float*)d_out);
}